// Round 4
// baseline (670.451 us; speedup 1.0000x reference)
//
#include <hip/hip_runtime.h>
#include <hip/hip_bf16.h>
#include <math.h>

#define NN   32768
#define BG   32
#define NPG  1024
#define HD   64
#define KK   24          // neighbors

#define FLTMAX 3.402823466e38f

typedef __attribute__((ext_vector_type(8))) short short8;
typedef __attribute__((ext_vector_type(4))) float f32x4;

__device__ __forceinline__ float elu1(float x) { return x > 0.f ? x : expm1f(x); }

__device__ __forceinline__ unsigned short f2bf(float x) {  // RNE truncate to bf16
  unsigned u = __float_as_uint(x);
  unsigned r = (u + 0x7FFFu + ((u >> 16) & 1u)) >> 16;
  return (unsigned short)r;
}
__device__ __forceinline__ float bf2f(unsigned short h) {
  return __uint_as_float(((unsigned)h) << 16);
}

// ---------------- input MLP: h = elu(elu(x@W1+b1)@W2+b2) ----------------
__global__ void __launch_bounds__(256) k_mlp_in(
    const float* __restrict__ x, const float* __restrict__ W1, const float* __restrict__ b1,
    const float* __restrict__ W2, const float* __restrict__ b2, float* __restrict__ F) {
  __shared__ float sW1[8*64];
  __shared__ float sW2[64*64];
  __shared__ float sb1[64];
  __shared__ float sb2[64];
  int t = threadIdx.x;
  for (int i = t; i < 8*64; i += 256) sW1[i] = W1[i];
  for (int i = t; i < 64*64; i += 256) sW2[i] = W2[i];
  if (t < 64) { sb1[t] = b1[t]; sb2[t] = b2[t]; }
  __syncthreads();
  int node = blockIdx.x*256 + t;
  float xr[8];
#pragma unroll
  for (int i = 0; i < 8; ++i) xr[i] = x[node*8 + i];
  float h1[64];
#pragma unroll 8
  for (int k = 0; k < 64; ++k) {
    float a = sb1[k];
#pragma unroll
    for (int i = 0; i < 8; ++i) a += xr[i]*sW1[i*64+k];
    h1[k] = elu1(a);
  }
#pragma unroll 2
  for (int d = 0; d < 64; ++d) {
    float a = sb2[d];
#pragma unroll
    for (int k = 0; k < 64; ++k) a += h1[k]*sW2[k*64+d];
    F[node*64 + d] = elu1(a);
  }
}

// ---------------- per-layer: U = X@(A-B)+bc, V = X@B, SQ = rowsum(X^2) ----------------
__global__ void __launch_bounds__(256) k_uv(
    const float* __restrict__ X, const float* __restrict__ Wc, const float* __restrict__ bc,
    float* __restrict__ U, float* __restrict__ V, float* __restrict__ SQ) {
  __shared__ float sA[64*64];
  __shared__ float sB[64*64];
  __shared__ float sbc[64];
  int t = threadIdx.x;
  for (int i = t; i < 64*64; i += 256) { sA[i] = Wc[i]; sB[i] = Wc[64*64 + i]; }
  if (t < 64) sbc[t] = bc[t];
  __syncthreads();
  int node = blockIdx.x*256 + t;
  float xr[64];
  float sq = 0.f;
#pragma unroll
  for (int k = 0; k < 64; ++k) { float v = X[node*64+k]; xr[k] = v; sq += v*v; }
  SQ[node] = sq;
#pragma unroll 2
  for (int d = 0; d < 64; ++d) {
    float ua = 0.f, vb = 0.f;
#pragma unroll
    for (int k = 0; k < 64; ++k) { ua += xr[k]*sA[k*64+d]; vb += xr[k]*sB[k*64+d]; }
    U[node*64+d] = ua - vb + sbc[d];
    V[node*64+d] = vb;
  }
}

// ---------------- helpers for knn selection ----------------
template<int R>
__device__ __forceinline__ void bitonic64(float (&kv)[R], int (&kc)[R], int lane) {
#pragma unroll
  for (int k = 2; k <= 64; k <<= 1) {
#pragma unroll
    for (int j = k >> 1; j > 0; j >>= 1) {
      bool keepmin = ((lane < (lane ^ j)) == ((lane & k) == 0));
#pragma unroll
      for (int r = 0; r < R; ++r) {
        float ov = __shfl_xor(kv[r], j);
        int   oc = __shfl_xor(kc[r], j);
        bool less = (ov < kv[r]) || (ov == kv[r] && oc < kc[r]);
        bool take = keepmin ? less : !less;
        if (take) { kv[r] = ov; kc[r] = oc; }
      }
    }
  }
}

// staged-column LDS addressing: node 0..511, granule 0..7 (16B units; hi k-oct 0..3, lo 4..7)
// XOR swizzle spreads the 16 nodes of a tile across banks; write & read share this helper.
__device__ __forceinline__ int col_byte(int node, int granule) {
  return node*128 + ((granule ^ (node & 7)) << 4);
}

// ---------------- knn: MFMA Gram (split bf16) + exact top-24 by (dist, idx) ----------------
// Block = 256 threads (4 waves), 16 rows of one graph.
// Gram: 64 tiles of 16x16 (wave w -> tiles w*8+tt per col-half), mfma_f32_16x16x32_bf16,
// G = HH^T + HL^T + LH^T + LL^T with x = hi + lo (two bf16), fp32 accumulate.
// Selection: proven register pipeline (v = csq - 2*dot; rsq is a per-row constant, rank-invariant).
__global__ void __launch_bounds__(256, 2) k_knn(
    const float* __restrict__ X, const float* __restrict__ SQ, int* __restrict__ IDX) {
  __shared__ __align__(16) unsigned char sRegion[65536]; // staging bf16 -> dist f32 -> sCmp
  __shared__ __align__(16) unsigned char sRowB[16*272];  // rows: [r][hi 128B | lo 128B | pad 16B]
  __shared__ float sCsq[1024];

  int g = blockIdx.x >> 6;
  int rowBase = (blockIdx.x & 63) * 16;
  int gbase = g * NPG;
  int t = threadIdx.x;
  const int lane = t & 63, wave = t >> 6;
  const int g4 = lane >> 4;      // 0..3
  const int a15 = lane & 15;

  // ---- stage row features (split bf16) + column squared norms ----
  {
    int r = t >> 4, k4 = (t & 15) * 4;
    float4 f = *reinterpret_cast<const float4*>(X + (size_t)(gbase + rowBase + r)*64 + k4);
    unsigned short h0 = f2bf(f.x), h1 = f2bf(f.y), h2 = f2bf(f.z), h3 = f2bf(f.w);
    unsigned short l0 = f2bf(f.x - bf2f(h0)), l1 = f2bf(f.y - bf2f(h1));
    unsigned short l2 = f2bf(f.z - bf2f(h2)), l3 = f2bf(f.w - bf2f(h3));
    uint2 hp = make_uint2((unsigned)h0 | ((unsigned)h1 << 16), (unsigned)h2 | ((unsigned)h3 << 16));
    uint2 lp = make_uint2((unsigned)l0 | ((unsigned)l1 << 16), (unsigned)l2 | ((unsigned)l3 << 16));
    *reinterpret_cast<uint2*>(sRowB + r*272 + k4*2)       = hp;
    *reinterpret_cast<uint2*>(sRowB + r*272 + 128 + k4*2) = lp;
    float4 q = *reinterpret_cast<const float4*>(SQ + gbase + t*4);
    *reinterpret_cast<float4*>(sCsq + t*4) = q;
  }

  f32x4 acc[16];
#pragma unroll
  for (int i = 0; i < 16; ++i) acc[i] = f32x4{0.f, 0.f, 0.f, 0.f};

  // ---- Gram: 2 col-halves x 2 K-slices ----
#pragma unroll
  for (int h = 0; h < 2; ++h) {
#pragma unroll
    for (int ks = 0; ks < 2; ++ks) {
      __syncthreads();
      // stage 512 nodes x 32 k (hi+lo) into sRegion
#pragma unroll
      for (int p = 0; p < 2; ++p) {
        int n = p*256 + t;
        const float* src = X + (size_t)(gbase + h*512 + n)*64 + ks*32;
        unsigned hu[16], lu[16];
#pragma unroll
        for (int q = 0; q < 8; ++q) {
          float4 f = *reinterpret_cast<const float4*>(src + q*4);
          unsigned short h0 = f2bf(f.x), h1 = f2bf(f.y), h2 = f2bf(f.z), h3 = f2bf(f.w);
          unsigned short l0 = f2bf(f.x - bf2f(h0)), l1 = f2bf(f.y - bf2f(h1));
          unsigned short l2 = f2bf(f.z - bf2f(h2)), l3 = f2bf(f.w - bf2f(h3));
          hu[q*2]   = (unsigned)h0 | ((unsigned)h1 << 16);
          hu[q*2+1] = (unsigned)h2 | ((unsigned)h3 << 16);
          lu[q*2]   = (unsigned)l0 | ((unsigned)l1 << 16);
          lu[q*2+1] = (unsigned)l2 | ((unsigned)l3 << 16);
        }
#pragma unroll
        for (int gr = 0; gr < 4; ++gr) {
          *reinterpret_cast<int4*>(sRegion + col_byte(n, gr)) =
            make_int4(hu[gr*4], hu[gr*4+1], hu[gr*4+2], hu[gr*4+3]);
          *reinterpret_cast<int4*>(sRegion + col_byte(n, 4 + gr)) =
            make_int4(lu[gr*4], lu[gr*4+1], lu[gr*4+2], lu[gr*4+3]);
        }
      }
      __syncthreads();
      // A fragments (rows), same for all tiles this slice
      short8 ah = *reinterpret_cast<const short8*>(sRowB + a15*272 + ks*64 + (g4 << 4));
      short8 al = *reinterpret_cast<const short8*>(sRowB + a15*272 + 128 + ks*64 + (g4 << 4));
#pragma unroll
      for (int tt = 0; tt < 8; ++tt) {
        int node = (wave*8 + tt)*16 + a15;
        short8 bh = *reinterpret_cast<const short8*>(sRegion + col_byte(node, g4));
        short8 bl = *reinterpret_cast<const short8*>(sRegion + col_byte(node, 4 + g4));
        int ai = h*8 + tt;
        acc[ai] = __builtin_amdgcn_mfma_f32_16x16x32_bf16(ah, bh, acc[ai], 0, 0, 0);
        acc[ai] = __builtin_amdgcn_mfma_f32_16x16x32_bf16(ah, bl, acc[ai], 0, 0, 0);
        acc[ai] = __builtin_amdgcn_mfma_f32_16x16x32_bf16(al, bh, acc[ai], 0, 0, 0);
        acc[ai] = __builtin_amdgcn_mfma_f32_16x16x32_bf16(al, bl, acc[ai], 0, 0, 0);
      }
    }
  }

  // ---- write v = csq - 2*G into dist LDS (reuses staging region) ----
  __syncthreads();
  float* dL = (float*)sRegion;   // [16][1024]
#pragma unroll
  for (int ai = 0; ai < 16; ++ai) {
    int c = (ai >> 3)*512 + (wave*8 + (ai & 7))*16 + a15;
    float cs = sCsq[c];
#pragma unroll
    for (int i = 0; i < 4; ++i) {
      int r = g4*4 + i;          // D row = (lane>>4)*4 + reg
      dL[r*1024 + c] = cs - 2.0f*acc[ai][i];
    }
  }
  __syncthreads();

  // ---- reload per-wave selection layout: wave w owns rows 4w..4w+3, lane owns cols lane+64m ----
  float v[4][16];
#pragma unroll
  for (int r = 0; r < 4; ++r)
#pragma unroll
    for (int m = 0; m < 16; ++m)
      v[r][m] = dL[(wave*4 + r)*1024 + lane + 64*m];
  __syncthreads();               // region about to be reused as sCmp

  unsigned long long* sCmp = (unsigned long long*)sRegion; // [4 waves][4 rows][64]

  // phase 2: per-lane argmin per row
  float lm[4]; int lc[4];
#pragma unroll
  for (int r = 0; r < 4; ++r) {
    float bm = v[r][0]; int bc = lane;
#pragma unroll
    for (int m = 1; m < 16; ++m) {
      float vv = v[r][m]; int cc = lane + (m<<6);
      bool b = vv < bm; bm = b ? vv : bm; bc = b ? cc : bc;
    }
    lm[r] = bm; lc[r] = bc;
  }

  // phase 3: sort lane-minima; thr = 24th smallest lane-min
  bitonic64<4>(lm, lc, lane);
  float thr[4];
#pragma unroll
  for (int r = 0; r < 4; ++r) thr[r] = __shfl(lm[r], 23);

  // phase 4: flag, prefix-scan, compact to LDS
  int total[4], excl[4]; unsigned fbits[4];
#pragma unroll
  for (int r = 0; r < 4; ++r) {
    unsigned bits = 0; int cnt = 0;
#pragma unroll
    for (int m = 0; m < 16; ++m) {
      bool f = v[r][m] <= thr[r];
      bits |= ((unsigned)f) << m; cnt += f;
    }
    int pre = cnt;
#pragma unroll
    for (int s = 1; s < 64; s <<= 1) { int o = __shfl_up(pre, s); if (lane >= s) pre += o; }
    total[r] = __shfl(pre, 63);
    excl[r] = pre - cnt; fbits[r] = bits;
  }
#pragma unroll
  for (int r = 0; r < 4; ++r) {
    int slot = excl[r];
#pragma unroll
    for (int m = 0; m < 16; ++m) {
      if ((fbits[r] >> m) & 1) {
        if (slot < 64)
          sCmp[(wave*4 + r)*64 + slot] =
            ((unsigned long long)__float_as_uint(v[r][m]) << 32) | (unsigned)(lane + (m<<6));
        ++slot;
      }
    }
  }
  __syncthreads();

  // phase 5/6: sort compacted candidates, emit top-24
  bool allfast = total[0] <= 64 && total[1] <= 64 && total[2] <= 64 && total[3] <= 64;
  long long ob0 = (long long)(gbase + rowBase + wave*4) * KK;
  if (allfast) {
    float sv[4]; int sc[4];
#pragma unroll
    for (int r = 0; r < 4; ++r) {
      bool in = lane < total[r];
      unsigned long long kp = in ? sCmp[(wave*4 + r)*64 + lane] : 0ull;
      sv[r] = in ? __uint_as_float((unsigned)(kp >> 32)) : FLTMAX;
      sc[r] = in ? (int)(unsigned)kp : 0x7fffffff;
    }
    bitonic64<4>(sv, sc, lane);
#pragma unroll
    for (int r = 0; r < 4; ++r)
      if (lane < KK) IDX[ob0 + (long long)r*KK + lane] = gbase + sc[r];
  } else {
    // cold exact path: fully inlined so v stays in registers
#pragma unroll
    for (int r = 0; r < 4; ++r) {
      unsigned selm = 0;
      for (int it = 0; it < KK; ++it) {
        float bv = FLTMAX; int bj = 0x7fffffff;
#pragma unroll
        for (int m = 0; m < 16; ++m) {
          float vv = ((selm >> m) & 1) ? FLTMAX : v[r][m];
          int col = lane + (m << 6);
          bool b = vv < bv; bv = b ? vv : bv; bj = b ? col : bj;
        }
#pragma unroll
        for (int s = 32; s; s >>= 1) {
          float ov = __shfl_xor(bv, s); int oj = __shfl_xor(bj, s);
          bool b = (ov < bv) || (ov == bv && oj < bj);
          bv = b ? ov : bv; bj = b ? oj : bj;
        }
        if (lane == (bj & 63)) selm |= 1u << (bj >> 6);
        if (lane == 0) IDX[ob0 + (long long)r*KK + it] = gbase + bj;
      }
    }
  }
}

// ---------------- aggregate: Fn = X + elu(U + max_j V[j]) ----------------
__global__ void __launch_bounds__(256) k_agg(
    const float* __restrict__ X, const float* __restrict__ U, const float* __restrict__ V,
    const int* __restrict__ IDX, float* __restrict__ Fn) {
  int tid = blockIdx.x*256 + threadIdx.x;
  int node = tid >> 6;
  int lane = tid & 63;
  const int* idx = IDX + (size_t)node*KK;
  float m = -FLTMAX;
#pragma unroll
  for (int t = 0; t < KK; ++t) {
    int j = idx[t];                          // wave-uniform
    m = fmaxf(m, V[(size_t)j*64 + lane]);
  }
  float s = U[(size_t)node*64 + lane] + m;
  Fn[(size_t)node*64 + lane] = X[(size_t)node*64 + lane] + elu1(s);
}

// ---------------- output MLP + batch passthrough ----------------
__global__ void __launch_bounds__(256) k_out(
    const float* __restrict__ F, const float* __restrict__ Wo1, const float* __restrict__ bo1,
    const float* __restrict__ Wo2, const float* __restrict__ bo2,
    const float* __restrict__ Wo3, const float* __restrict__ bo3,
    const int* __restrict__ batch, float* __restrict__ out, int out_size) {
  __shared__ float s1[64*64];
  __shared__ float s2[64*32];
  __shared__ float s3[32*8];
  __shared__ float t1[64];
  __shared__ float t2[32];
  __shared__ float t3[8];
  int t = threadIdx.x;
  for (int i = t; i < 64*64; i += 256) s1[i] = Wo1[i];
  for (int i = t; i < 64*32; i += 256) s2[i] = Wo2[i];
  if (t < 32*8) s3[t] = Wo3[t];
  if (t < 64) t1[t] = bo1[t];
  if (t < 32) t2[t] = bo2[t];
  if (t < 8)  t3[t] = bo3[t];
  __syncthreads();
  int node = blockIdx.x*256 + t;
  float f[64];
#pragma unroll
  for (int k = 0; k < 64; ++k) f[k] = F[(size_t)node*64 + k];
  float o1[64];
#pragma unroll 2
  for (int d = 0; d < 64; ++d) {
    float a = t1[d];
#pragma unroll
    for (int k = 0; k < 64; ++k) a += f[k]*s1[k*64+d];
    o1[d] = elu1(a);
  }
  float o2[32];
#pragma unroll 2
  for (int d = 0; d < 32; ++d) {
    float a = t2[d];
#pragma unroll
    for (int k = 0; k < 64; ++k) a += o1[k]*s2[k*32+d];
    o2[d] = elu1(a);
  }
#pragma unroll
  for (int d = 0; d < 8; ++d) {
    float a = t3[d];
#pragma unroll
    for (int k = 0; k < 32; ++k) a += o2[k]*s3[k*8+d];
    out[(size_t)node*8 + d] = a;
  }
  if (out_size >= NN*9) out[(size_t)NN*8 + node] = (float)batch[node];
}

extern "C" void kernel_launch(void* const* d_in, const int* in_sizes, int n_in,
                              void* d_out, int out_size, void* d_ws, size_t ws_size,
                              hipStream_t stream) {
  const float* x     = (const float*)d_in[0];
  const int*   batch = (const int*)d_in[1];
  const float* W1 = (const float*)d_in[2];
  const float* b1 = (const float*)d_in[3];
  const float* W2 = (const float*)d_in[4];
  const float* b2 = (const float*)d_in[5];
  const float* Wc[3] = {(const float*)d_in[6], (const float*)d_in[8], (const float*)d_in[10]};
  const float* bc[3] = {(const float*)d_in[7], (const float*)d_in[9], (const float*)d_in[11]};
  const float* Wo1 = (const float*)d_in[12];
  const float* bo1 = (const float*)d_in[13];
  const float* Wo2 = (const float*)d_in[14];
  const float* bo2 = (const float*)d_in[15];
  const float* Wo3 = (const float*)d_in[16];
  const float* bo3 = (const float*)d_in[17];

  float* ws = (float*)d_ws;
  float* F0 = ws;
  float* F1 = ws + (size_t)NN*64;
  float* U  = ws + (size_t)2*NN*64;
  float* V  = ws + (size_t)3*NN*64;
  float* SQ = ws + (size_t)4*NN*64;
  int*   IDX = (int*)(ws + (size_t)4*NN*64 + NN);

  k_mlp_in<<<NN/256, 256, 0, stream>>>(x, W1, b1, W2, b2, F0);
  float* cur = F0;
  float* nxt = F1;
  for (int l = 0; l < 3; ++l) {
    k_uv <<<NN/256, 256, 0, stream>>>(cur, Wc[l], bc[l], U, V, SQ);
    k_knn<<<BG*(NPG/16), 256, 0, stream>>>(cur, SQ, IDX);
    k_agg<<<(NN*64)/256, 256, 0, stream>>>(cur, U, V, IDX, nxt);
    float* tmp = cur; cur = nxt; nxt = tmp;
  }
  k_out<<<NN/256, 256, 0, stream>>>(cur, Wo1, bo1, Wo2, bo2, Wo3, bo3,
                                    batch, (float*)d_out, out_size);
}

// Round 5
// 566.354 us; speedup vs baseline: 1.1838x; 1.1838x over previous
//
#include <hip/hip_runtime.h>
#include <hip/hip_bf16.h>
#include <math.h>

#define NN   32768
#define BG   32
#define NPG  1024
#define HD   64
#define KK   24          // neighbors

#define FLTMAX 3.402823466e38f

typedef __attribute__((ext_vector_type(8))) short short8;
typedef __attribute__((ext_vector_type(4))) float f32x4;

__device__ __forceinline__ float elu1(float x) { return x > 0.f ? x : expm1f(x); }

__device__ __forceinline__ unsigned short f2bf(float x) {  // RNE to bf16
  unsigned u = __float_as_uint(x);
  unsigned r = (u + 0x7FFFu + ((u >> 16) & 1u)) >> 16;
  return (unsigned short)r;
}
__device__ __forceinline__ float bf2f(unsigned short h) {
  return __uint_as_float(((unsigned)h) << 16);
}

// async global->LDS, 16B per lane; lds base must be wave-uniform (HW adds lane*16)
__device__ __forceinline__ void gl_lds16(const void* g, void* lds) {
  __builtin_amdgcn_global_load_lds(
      (const __attribute__((address_space(1))) unsigned int*)g,
      (__attribute__((address_space(3))) unsigned int*)lds, 16, 0, 0);
}

// ---------------- input MLP: h = elu(elu(x@W1+b1)@W2+b2) ----------------
__global__ void __launch_bounds__(256) k_mlp_in(
    const float* __restrict__ x, const float* __restrict__ W1, const float* __restrict__ b1,
    const float* __restrict__ W2, const float* __restrict__ b2, float* __restrict__ F) {
  __shared__ float sW1[8*64];
  __shared__ float sW2[64*64];
  __shared__ float sb1[64];
  __shared__ float sb2[64];
  int t = threadIdx.x;
  for (int i = t; i < 8*64; i += 256) sW1[i] = W1[i];
  for (int i = t; i < 64*64; i += 256) sW2[i] = W2[i];
  if (t < 64) { sb1[t] = b1[t]; sb2[t] = b2[t]; }
  __syncthreads();
  int node = blockIdx.x*256 + t;
  float xr[8];
#pragma unroll
  for (int i = 0; i < 8; ++i) xr[i] = x[node*8 + i];
  float h1[64];
#pragma unroll 8
  for (int k = 0; k < 64; ++k) {
    float a = sb1[k];
#pragma unroll
    for (int i = 0; i < 8; ++i) a += xr[i]*sW1[i*64+k];
    h1[k] = elu1(a);
  }
#pragma unroll 2
  for (int d = 0; d < 64; ++d) {
    float a = sb2[d];
#pragma unroll
    for (int k = 0; k < 64; ++k) a += h1[k]*sW2[k*64+d];
    F[node*64 + d] = elu1(a);
  }
}

// ---- per-layer: U = X@(A-B)+bc, V = X@B, SQ = rowsum(X^2), XB = split-bf16(X) ----
// XB layout: [graph][ks(0..1)][node 0..1023][hi 4x16B | lo 4x16B]  (128B per node-slice)
//   slice ks covers k = ks*32 .. ks*32+31; oct o within slice = k (o*8..o*8+7).
__global__ void __launch_bounds__(256) k_uv(
    const float* __restrict__ X, const float* __restrict__ Wc, const float* __restrict__ bc,
    float* __restrict__ U, float* __restrict__ V, float* __restrict__ SQ,
    unsigned char* __restrict__ XB) {
  __shared__ float sA[64*64];
  __shared__ float sB[64*64];
  __shared__ float sbc[64];
  int t = threadIdx.x;
  for (int i = t; i < 64*64; i += 256) { sA[i] = Wc[i]; sB[i] = Wc[64*64 + i]; }
  if (t < 64) sbc[t] = bc[t];
  __syncthreads();
  int node = blockIdx.x*256 + t;
  float xr[64];
  float sq = 0.f;
#pragma unroll
  for (int k = 0; k < 64; ++k) { float v = X[node*64+k]; xr[k] = v; sq += v*v; }
  SQ[node] = sq;

  // split-bf16 write-out
  {
    int g5 = node >> 10, n = node & 1023;
#pragma unroll
    for (int ks = 0; ks < 2; ++ks) {
      unsigned char* dst = XB + (((size_t)g5*2 + ks)*1024 + n)*128;
#pragma unroll
      for (int q = 0; q < 4; ++q) {
        unsigned hh[4], ll[4];
#pragma unroll
        for (int w2 = 0; w2 < 4; ++w2) {
          float x0 = xr[ks*32 + q*8 + w2*2], x1 = xr[ks*32 + q*8 + w2*2 + 1];
          unsigned short h0 = f2bf(x0), h1 = f2bf(x1);
          unsigned short l0 = f2bf(x0 - bf2f(h0)), l1 = f2bf(x1 - bf2f(h1));
          hh[w2] = (unsigned)h0 | ((unsigned)h1 << 16);
          ll[w2] = (unsigned)l0 | ((unsigned)l1 << 16);
        }
        *reinterpret_cast<int4*>(dst + q*16)      = make_int4(hh[0], hh[1], hh[2], hh[3]);
        *reinterpret_cast<int4*>(dst + 64 + q*16) = make_int4(ll[0], ll[1], ll[2], ll[3]);
      }
    }
  }

#pragma unroll 2
  for (int d = 0; d < 64; ++d) {
    float ua = 0.f, vb = 0.f;
#pragma unroll
    for (int k = 0; k < 64; ++k) { ua += xr[k]*sA[k*64+d]; vb += xr[k]*sB[k*64+d]; }
    U[node*64+d] = ua - vb + sbc[d];
    V[node*64+d] = vb;
  }
}

// ---------------- helpers for knn selection ----------------
template<int R>
__device__ __forceinline__ void bitonic64(float (&kv)[R], int (&kc)[R], int lane) {
#pragma unroll
  for (int k = 2; k <= 64; k <<= 1) {
#pragma unroll
    for (int j = k >> 1; j > 0; j >>= 1) {
      bool keepmin = ((lane < (lane ^ j)) == ((lane & k) == 0));
#pragma unroll
      for (int r = 0; r < R; ++r) {
        float ov = __shfl_xor(kv[r], j);
        int   oc = __shfl_xor(kc[r], j);
        bool less = (ov < kv[r]) || (ov == kv[r] && oc < kc[r]);
        bool take = keepmin ? less : !less;
        if (take) { kv[r] = ov; kc[r] = oc; }
      }
    }
  }
}

// read-side LDS addressing: node 0..511, granule 0..7 (hi 0..3, lo 4..7), XOR bank swizzle.
// Write side is LINEAR (global_load_lds); the swizzle is applied to the global SOURCE
// address instead (same involution), so read must use this helper.
__device__ __forceinline__ int col_byte(int node, int granule) {
  return node*128 + ((granule ^ (node & 7)) << 4);
}

// ---------------- knn: MFMA Gram (split bf16, precomputed) + exact top-24 ----------------
__global__ void __launch_bounds__(256, 2) k_knn(
    const unsigned char* __restrict__ XB, const float* __restrict__ SQ,
    int* __restrict__ IDX) {
  __shared__ __align__(16) unsigned char sRegion[65536]; // staging bf16 -> dist f32 -> sCmp
  __shared__ __align__(16) unsigned char sRowB[16*272];  // [row][ks0 hi|lo, ks1 hi|lo] + pad
  __shared__ float sCsq[1024];

  int g = blockIdx.x >> 6;
  int rowBase = (blockIdx.x & 63) * 16;
  int gbase = g * NPG;
  int t = threadIdx.x;
  const int lane = t & 63, wave = t >> 6;
  const int g4 = lane >> 4;      // 0..3
  const int a15 = lane & 15;

  // ---- stage row fragments + column squared norms ----
  {
    int row = t >> 4, part = t & 15;          // part<8 -> ks0, else ks1
    int ks = part >> 3, o = part & 7;
    const unsigned char* src =
        XB + (((size_t)g*2 + ks)*1024 + rowBase + row)*128 + o*16;
    *reinterpret_cast<int4*>(sRowB + row*272 + part*16) =
        *reinterpret_cast<const int4*>(src);
    float4 q = *reinterpret_cast<const float4*>(SQ + gbase + t*4);
    *reinterpret_cast<float4*>(sCsq + t*4) = q;
  }
  __syncthreads();

  // A fragments, both k-slices, hoisted (sRowB stable from here on)
  short8 ahf[2], alf[2];
#pragma unroll
  for (int ks = 0; ks < 2; ++ks) {
    ahf[ks] = *reinterpret_cast<const short8*>(sRowB + a15*272 + ks*128 + (g4 << 4));
    alf[ks] = *reinterpret_cast<const short8*>(sRowB + a15*272 + ks*128 + 64 + (g4 << 4));
  }

  f32x4 acc[16];
#pragma unroll
  for (int i = 0; i < 16; ++i) acc[i] = f32x4{0.f, 0.f, 0.f, 0.f};

  // ---- Gram: 2 col-halves x 2 K-slices; async staged 64KB per stage ----
#pragma unroll
  for (int h = 0; h < 2; ++h) {
#pragma unroll
    for (int ks = 0; ks < 2; ++ks) {
      __syncthreads();
      const unsigned char* sl = XB + (((size_t)g*2 + ks)*1024 + h*512)*128;
      // 64 x 1KB wave-instructions; wave owns I = wave*16 + i.
      // LDS linear slot j = I*64+lane -> (node j>>3, gran j&7); source granule
      // pre-swizzled: srcChunk = node*8 + ((j&7) ^ (node&7)).
#pragma unroll
      for (int i = 0; i < 16; ++i) {
        int I = wave*16 + i;
        int j = I*64 + lane;
        int n = j >> 3, q = j & 7;
        int srcChunk = (n << 3) + (q ^ (n & 7));
        gl_lds16(sl + (size_t)srcChunk*16, (void*)(sRegion + I*1024));
      }
      __syncthreads();
#pragma unroll
      for (int tt = 0; tt < 8; ++tt) {
        int node = (wave*8 + tt)*16 + a15;
        short8 bh = *reinterpret_cast<const short8*>(sRegion + col_byte(node, g4));
        short8 bl = *reinterpret_cast<const short8*>(sRegion + col_byte(node, 4 + g4));
        int ai = h*8 + tt;
        acc[ai] = __builtin_amdgcn_mfma_f32_16x16x32_bf16(ahf[ks], bh, acc[ai], 0, 0, 0);
        acc[ai] = __builtin_amdgcn_mfma_f32_16x16x32_bf16(ahf[ks], bl, acc[ai], 0, 0, 0);
        acc[ai] = __builtin_amdgcn_mfma_f32_16x16x32_bf16(alf[ks], bh, acc[ai], 0, 0, 0);
        acc[ai] = __builtin_amdgcn_mfma_f32_16x16x32_bf16(alf[ks], bl, acc[ai], 0, 0, 0);
      }
    }
  }

  // ---- write v = csq - 2*G into dist LDS (reuses staging region) ----
  __syncthreads();
  float* dL = (float*)sRegion;   // [16][1024]
#pragma unroll
  for (int ai = 0; ai < 16; ++ai) {
    int c = (ai >> 3)*512 + (wave*8 + (ai & 7))*16 + a15;
    float cs = sCsq[c];
#pragma unroll
    for (int i = 0; i < 4; ++i) {
      int r = g4*4 + i;          // D row = (lane>>4)*4 + reg
      dL[r*1024 + c] = cs - 2.0f*acc[ai][i];
    }
  }
  __syncthreads();

  // ---- selection layout: wave w owns rows 4w..4w+3, lane owns cols lane+64m ----
  float v[4][16];
#pragma unroll
  for (int r = 0; r < 4; ++r)
#pragma unroll
    for (int m = 0; m < 16; ++m)
      v[r][m] = dL[(wave*4 + r)*1024 + lane + 64*m];
  __syncthreads();               // region about to be reused as sCmp

  unsigned long long* sCmp = (unsigned long long*)sRegion; // [4 waves][4 rows][64]

  // phase 2: per-lane argmin per row
  float lm[4]; int lc[4];
#pragma unroll
  for (int r = 0; r < 4; ++r) {
    float bm = v[r][0]; int bc = lane;
#pragma unroll
    for (int m = 1; m < 16; ++m) {
      float vv = v[r][m]; int cc = lane + (m<<6);
      bool b = vv < bm; bm = b ? vv : bm; bc = b ? cc : bc;
    }
    lm[r] = bm; lc[r] = bc;
  }

  // phase 3: sort lane-minima; thr = 24th smallest lane-min
  bitonic64<4>(lm, lc, lane);
  float thr[4];
#pragma unroll
  for (int r = 0; r < 4; ++r) thr[r] = __shfl(lm[r], 23);

  // phase 4: flag, prefix-scan, compact to LDS
  int total[4], excl[4]; unsigned fbits[4];
#pragma unroll
  for (int r = 0; r < 4; ++r) {
    unsigned bits = 0; int cnt = 0;
#pragma unroll
    for (int m = 0; m < 16; ++m) {
      bool f = v[r][m] <= thr[r];
      bits |= ((unsigned)f) << m; cnt += f;
    }
    int pre = cnt;
#pragma unroll
    for (int s = 1; s < 64; s <<= 1) { int o = __shfl_up(pre, s); if (lane >= s) pre += o; }
    total[r] = __shfl(pre, 63);
    excl[r] = pre - cnt; fbits[r] = bits;
  }
#pragma unroll
  for (int r = 0; r < 4; ++r) {
    int slot = excl[r];
#pragma unroll
    for (int m = 0; m < 16; ++m) {
      if ((fbits[r] >> m) & 1) {
        if (slot < 64)
          sCmp[(wave*4 + r)*64 + slot] =
            ((unsigned long long)__float_as_uint(v[r][m]) << 32) | (unsigned)(lane + (m<<6));
        ++slot;
      }
    }
  }
  __syncthreads();

  // phase 5/6: sort compacted candidates, emit top-24
  bool allfast = total[0] <= 64 && total[1] <= 64 && total[2] <= 64 && total[3] <= 64;
  long long ob0 = (long long)(gbase + rowBase + wave*4) * KK;
  if (allfast) {
    float sv[4]; int sc[4];
#pragma unroll
    for (int r = 0; r < 4; ++r) {
      bool in = lane < total[r];
      unsigned long long kp = in ? sCmp[(wave*4 + r)*64 + lane] : 0ull;
      sv[r] = in ? __uint_as_float((unsigned)(kp >> 32)) : FLTMAX;
      sc[r] = in ? (int)(unsigned)kp : 0x7fffffff;
    }
    bitonic64<4>(sv, sc, lane);
#pragma unroll
    for (int r = 0; r < 4; ++r)
      if (lane < KK) IDX[ob0 + (long long)r*KK + lane] = gbase + sc[r];
  } else {
    // cold exact path: fully inlined so v stays in registers
#pragma unroll
    for (int r = 0; r < 4; ++r) {
      unsigned selm = 0;
      for (int it = 0; it < KK; ++it) {
        float bv = FLTMAX; int bj = 0x7fffffff;
#pragma unroll
        for (int m = 0; m < 16; ++m) {
          float vv = ((selm >> m) & 1) ? FLTMAX : v[r][m];
          int col = lane + (m << 6);
          bool b = vv < bv; bv = b ? vv : bv; bj = b ? col : bj;
        }
#pragma unroll
        for (int s = 32; s; s >>= 1) {
          float ov = __shfl_xor(bv, s); int oj = __shfl_xor(bj, s);
          bool b = (ov < bv) || (ov == bv && oj < bj);
          bv = b ? ov : bv; bj = b ? oj : bj;
        }
        if (lane == (bj & 63)) selm |= 1u << (bj >> 6);
        if (lane == 0) IDX[ob0 + (long long)r*KK + it] = gbase + bj;
      }
    }
  }
}

// ---------------- aggregate (in place): F = X + elu(U + max_j V[j]) ----------------
__global__ void __launch_bounds__(256) k_agg(
    const float* __restrict__ U, const float* __restrict__ V,
    const int* __restrict__ IDX, float* __restrict__ F) {
  int tid = blockIdx.x*256 + threadIdx.x;
  int node = tid >> 6;
  int lane = tid & 63;
  const int* idx = IDX + (size_t)node*KK;
  float m = -FLTMAX;
#pragma unroll
  for (int t = 0; t < KK; ++t) {
    int j = idx[t];                          // wave-uniform
    m = fmaxf(m, V[(size_t)j*64 + lane]);
  }
  float s = U[(size_t)node*64 + lane] + m;
  F[(size_t)node*64 + lane] = F[(size_t)node*64 + lane] + elu1(s);
}

// ---------------- output MLP + batch passthrough ----------------
__global__ void __launch_bounds__(256) k_out(
    const float* __restrict__ F, const float* __restrict__ Wo1, const float* __restrict__ bo1,
    const float* __restrict__ Wo2, const float* __restrict__ bo2,
    const float* __restrict__ Wo3, const float* __restrict__ bo3,
    const int* __restrict__ batch, float* __restrict__ out, int out_size) {
  __shared__ float s1[64*64];
  __shared__ float s2[64*32];
  __shared__ float s3[32*8];
  __shared__ float t1[64];
  __shared__ float t2[32];
  __shared__ float t3[8];
  int t = threadIdx.x;
  for (int i = t; i < 64*64; i += 256) s1[i] = Wo1[i];
  for (int i = t; i < 64*32; i += 256) s2[i] = Wo2[i];
  if (t < 32*8) s3[t] = Wo3[t];
  if (t < 64) t1[t] = bo1[t];
  if (t < 32) t2[t] = bo2[t];
  if (t < 8)  t3[t] = bo3[t];
  __syncthreads();
  int node = blockIdx.x*256 + t;
  float f[64];
#pragma unroll
  for (int k = 0; k < 64; ++k) f[k] = F[(size_t)node*64 + k];
  float o1[64];
#pragma unroll 2
  for (int d = 0; d < 64; ++d) {
    float a = t1[d];
#pragma unroll
    for (int k = 0; k < 64; ++k) a += f[k]*s1[k*64+d];
    o1[d] = elu1(a);
  }
  float o2[32];
#pragma unroll 2
  for (int d = 0; d < 32; ++d) {
    float a = t2[d];
#pragma unroll
    for (int k = 0; k < 64; ++k) a += o1[k]*s2[k*32+d];
    o2[d] = elu1(a);
  }
#pragma unroll
  for (int d = 0; d < 8; ++d) {
    float a = t3[d];
#pragma unroll
    for (int k = 0; k < 32; ++k) a += o2[k]*s3[k*8+d];
    out[(size_t)node*8 + d] = a;
  }
  if (out_size >= NN*9) out[(size_t)NN*8 + node] = (float)batch[node];
}

extern "C" void kernel_launch(void* const* d_in, const int* in_sizes, int n_in,
                              void* d_out, int out_size, void* d_ws, size_t ws_size,
                              hipStream_t stream) {
  const float* x     = (const float*)d_in[0];
  const int*   batch = (const int*)d_in[1];
  const float* W1 = (const float*)d_in[2];
  const float* b1 = (const float*)d_in[3];
  const float* W2 = (const float*)d_in[4];
  const float* b2 = (const float*)d_in[5];
  const float* Wc[3] = {(const float*)d_in[6], (const float*)d_in[8], (const float*)d_in[10]};
  const float* bc[3] = {(const float*)d_in[7], (const float*)d_in[9], (const float*)d_in[11]};
  const float* Wo1 = (const float*)d_in[12];
  const float* bo1 = (const float*)d_in[13];
  const float* Wo2 = (const float*)d_in[14];
  const float* bo2 = (const float*)d_in[15];
  const float* Wo3 = (const float*)d_in[16];
  const float* bo3 = (const float*)d_in[17];

  float* ws = (float*)d_ws;
  float* F0 = ws;                               // 8 MB (updated in place per layer)
  float* U  = ws + (size_t)NN*64;               // 8 MB
  float* V  = ws + (size_t)2*NN*64;             // 8 MB
  float* SQ = ws + (size_t)3*NN*64;             // 128 KB
  int*   IDX = (int*)(ws + (size_t)3*NN*64 + NN);           // 3 MB
  unsigned char* XB = (unsigned char*)(IDX + (size_t)NN*KK); // 8 MB split-bf16

  k_mlp_in<<<NN/256, 256, 0, stream>>>(x, W1, b1, W2, b2, F0);
  for (int l = 0; l < 3; ++l) {
    k_uv <<<NN/256, 256, 0, stream>>>(F0, Wc[l], bc[l], U, V, SQ, XB);
    k_knn<<<BG*(NPG/16), 256, 0, stream>>>(XB, SQ, IDX);
    k_agg<<<(NN*64)/256, 256, 0, stream>>>(U, V, IDX, F0);
  }
  k_out<<<NN/256, 256, 0, stream>>>(F0, Wo1, bo1, Wo2, bo2, Wo3, bo3,
                                    batch, (float*)d_out, out_size);
}

// Round 6
// 454.833 us; speedup vs baseline: 1.4741x; 1.2452x over previous
//
#include <hip/hip_runtime.h>
#include <hip/hip_bf16.h>
#include <math.h>

#define NN   32768
#define BG   32
#define NPG  1024
#define HD   64
#define KK   24          // neighbors

#define FLTMAX 3.402823466e38f

typedef __attribute__((ext_vector_type(8))) short short8;
typedef __attribute__((ext_vector_type(4))) float f32x4;

__device__ __forceinline__ float elu1(float x) { return x > 0.f ? x : expm1f(x); }

__device__ __forceinline__ unsigned short f2bf(float x) {  // RNE to bf16
  unsigned u = __float_as_uint(x);
  unsigned r = (u + 0x7FFFu + ((u >> 16) & 1u)) >> 16;
  return (unsigned short)r;
}
__device__ __forceinline__ float bf2f(unsigned short h) {
  return __uint_as_float(((unsigned)h) << 16);
}

// async global->LDS, 16B per lane; lds base must be wave-uniform (HW adds lane*16)
__device__ __forceinline__ void gl_lds16(const void* g, void* lds) {
  __builtin_amdgcn_global_load_lds(
      (const __attribute__((address_space(1))) unsigned int*)g,
      (__attribute__((address_space(3))) unsigned int*)lds, 16, 0, 0);
}

// ---------------- input MLP: h = elu(elu(x@W1+b1)@W2+b2) ----------------
// 2 threads per node (half = t>>7 computes 32 of the 64 outputs); h1 computed
// redundantly per thread (cheap) so grid doubles to fill all CUs.
__global__ void __launch_bounds__(256) k_mlp_in(
    const float* __restrict__ x, const float* __restrict__ W1, const float* __restrict__ b1,
    const float* __restrict__ W2, const float* __restrict__ b2, float* __restrict__ F) {
  __shared__ float sW1[8*64];
  __shared__ float sW2[64*64];
  __shared__ float sb1[64];
  __shared__ float sb2[64];
  int t = threadIdx.x;
  for (int i = t; i < 8*64; i += 256) sW1[i] = W1[i];
  for (int i = t; i < 64*64; i += 256) sW2[i] = W2[i];
  if (t < 64) { sb1[t] = b1[t]; sb2[t] = b2[t]; }
  __syncthreads();
  int node = blockIdx.x*128 + (t & 127);
  int half = t >> 7;
  float xr[8];
#pragma unroll
  for (int i = 0; i < 8; ++i) xr[i] = x[node*8 + i];
  float h1[64];
#pragma unroll 8
  for (int k = 0; k < 64; ++k) {
    float a = sb1[k];
#pragma unroll
    for (int i = 0; i < 8; ++i) a += xr[i]*sW1[i*64+k];
    h1[k] = elu1(a);
  }
#pragma unroll 2
  for (int dd = 0; dd < 32; ++dd) {
    int d = half*32 + dd;
    float a = sb2[d];
#pragma unroll
    for (int k = 0; k < 64; ++k) a += h1[k]*sW2[k*64+d];
    F[node*64 + d] = elu1(a);
  }
}

// split-bf16 conv-buffer addressing: per node 16 granules of 16B,
// g = ks*8 + part*4 + oct (part 0=hi,1=lo); XOR swizzle on low 3 bits.
__device__ __forceinline__ int conv_off(int node, int g) {
  return node*256 + ((((g & 7) ^ (node & 7)) | (g & 8)) << 4);
}

// ---- per-layer (MFMA): U = X@(A-B)+bc, V = X@B, SQ, XB = split-bf16(X) ----
// Block = 256 threads / 128 nodes. Converts its own rows to split-bf16 in LDS
// (also written out as XB for k_knn), stages Wc as B-fragments, then
// 4-way-split MFMA GEMM X[128x64] @ [A|B][64x128].
// XB global layout (consumed by k_knn): [graph][ks][node][hi 4x16B | lo 4x16B].
__global__ void __launch_bounds__(256) k_uv(
    const float* __restrict__ X, const float* __restrict__ Wc, const float* __restrict__ bc,
    float* __restrict__ U, float* __restrict__ V, float* __restrict__ SQ,
    unsigned char* __restrict__ XB) {
  __shared__ __align__(16) unsigned char sConv[128*256];   // 32 KB node rows (swizzled)
  __shared__ __align__(16) unsigned char sWf[128*256];     // 32 KB B-fragments
  __shared__ float sbc[64];
  int t = threadIdx.x;
  const int lane = t & 63, wave = t >> 6;
  const int g4 = lane >> 4, a15 = lane & 15;
  int base = blockIdx.x * 128;                 // 128 | 1024 so block stays in one graph
  int graph = base >> 10;
  int nig0 = base & 1023;                      // node-in-graph of local node 0

  if (t < 64) sbc[t] = bc[t];

  // ---- phase A: convert 128 rows to split-bf16 (LDS + global XB), SQ ----
  {
    int ln = t >> 1, ks = t & 1;               // local node, k-slice
    const float* src = X + (size_t)(base + ln)*64 + ks*32;
    unsigned hu[16], lu[16];
    float sq = 0.f;
#pragma unroll
    for (int q = 0; q < 8; ++q) {
      float4 f = *reinterpret_cast<const float4*>(src + q*4);
      sq += f.x*f.x + f.y*f.y + f.z*f.z + f.w*f.w;
      unsigned short h0 = f2bf(f.x), h1 = f2bf(f.y), h2 = f2bf(f.z), h3 = f2bf(f.w);
      unsigned short l0 = f2bf(f.x - bf2f(h0)), l1 = f2bf(f.y - bf2f(h1));
      unsigned short l2 = f2bf(f.z - bf2f(h2)), l3 = f2bf(f.w - bf2f(h3));
      hu[q*2]   = (unsigned)h0 | ((unsigned)h1 << 16);
      hu[q*2+1] = (unsigned)h2 | ((unsigned)h3 << 16);
      lu[q*2]   = (unsigned)l0 | ((unsigned)l1 << 16);
      lu[q*2+1] = (unsigned)l2 | ((unsigned)l3 << 16);
    }
    // full-node squared norm via pair exchange (lanes 2n,2n+1 adjacent)
    sq += __shfl_xor(sq, 1);
    if (ks == 0) SQ[base + ln] = sq;
    unsigned char* gdst = XB + (((size_t)graph*2 + ks)*1024 + nig0 + ln)*128;
#pragma unroll
    for (int o = 0; o < 4; ++o) {
      int4 hp = make_int4(hu[o*4], hu[o*4+1], hu[o*4+2], hu[o*4+3]);
      int4 lp = make_int4(lu[o*4], lu[o*4+1], lu[o*4+2], lu[o*4+3]);
      *reinterpret_cast<int4*>(sConv + conv_off(ln, ks*8 + o))     = hp;
      *reinterpret_cast<int4*>(sConv + conv_off(ln, ks*8 + 4 + o)) = lp;
      *reinterpret_cast<int4*>(gdst + o*16)      = hp;
      *reinterpret_cast<int4*>(gdst + 64 + o*16) = lp;
    }
  }

  // ---- phase B: build W fragments: f = ((ks*4+oct)*8+nt)*2+part, 16 cols x 16B ----
  {
    int f = t >> 1, colHalf = t & 1;
    int part = f & 1, nt = (f >> 1) & 7, oct = (f >> 4) & 3, ks = f >> 6;
#pragma unroll
    for (int cc = 0; cc < 8; ++cc) {
      int c8 = colHalf*8 + cc;
      int dp = nt*16 + c8;                      // 0..127 output col
      const float* wsrc = (dp < 64) ? (Wc + dp) : (Wc + 64*64 + (dp - 64));
      unsigned short sh[8];
#pragma unroll
      for (int j = 0; j < 8; ++j) {
        float w = wsrc[(ks*32 + oct*8 + j)*64];
        unsigned short hi = f2bf(w);
        sh[j] = part ? f2bf(w - bf2f(hi)) : hi;
      }
      *reinterpret_cast<int4*>(sWf + f*256 + c8*16) = make_int4(
          (unsigned)sh[0] | ((unsigned)sh[1] << 16), (unsigned)sh[2] | ((unsigned)sh[3] << 16),
          (unsigned)sh[4] | ((unsigned)sh[5] << 16), (unsigned)sh[6] | ((unsigned)sh[7] << 16));
    }
  }
  __syncthreads();

  // ---- phase C: MFMA. wave handles M-tiles mt = wave*2 + {0,1} ----
  f32x4 acc[2][8];
#pragma unroll
  for (int m = 0; m < 2; ++m)
#pragma unroll
    for (int n = 0; n < 8; ++n) acc[m][n] = f32x4{0.f, 0.f, 0.f, 0.f};
#pragma unroll
  for (int ks = 0; ks < 2; ++ks) {
#pragma unroll
    for (int m = 0; m < 2; ++m) {
      int node = (wave*2 + m)*16 + a15;
      short8 ah = *reinterpret_cast<const short8*>(sConv + conv_off(node, ks*8 + g4));
      short8 al = *reinterpret_cast<const short8*>(sConv + conv_off(node, ks*8 + 4 + g4));
#pragma unroll
      for (int nt = 0; nt < 8; ++nt) {
        int fb = ((ks*4 + g4)*8 + nt)*2;
        short8 bh = *reinterpret_cast<const short8*>(sWf + fb*256 + a15*16);
        short8 bl = *reinterpret_cast<const short8*>(sWf + (fb+1)*256 + a15*16);
        acc[m][nt] = __builtin_amdgcn_mfma_f32_16x16x32_bf16(ah, bh, acc[m][nt], 0, 0, 0);
        acc[m][nt] = __builtin_amdgcn_mfma_f32_16x16x32_bf16(ah, bl, acc[m][nt], 0, 0, 0);
        acc[m][nt] = __builtin_amdgcn_mfma_f32_16x16x32_bf16(al, bh, acc[m][nt], 0, 0, 0);
        acc[m][nt] = __builtin_amdgcn_mfma_f32_16x16x32_bf16(al, bl, acc[m][nt], 0, 0, 0);
      }
    }
  }

  // ---- phase D: epilogue. row = base + mt*16 + g4*4 + i; col = nt*16 + a15 ----
#pragma unroll
  for (int m = 0; m < 2; ++m) {
#pragma unroll
    for (int nt = 0; nt < 4; ++nt) {
      float bcv = sbc[nt*16 + a15];
#pragma unroll
      for (int i = 0; i < 4; ++i) {
        size_t row = base + (wave*2 + m)*16 + g4*4 + i;
        float p = acc[m][nt][i], q = acc[m][nt+4][i];
        U[row*64 + nt*16 + a15] = p - q + bcv;
        V[row*64 + nt*16 + a15] = q;
      }
    }
  }
}

// ---------------- helpers for knn selection ----------------
template<int R>
__device__ __forceinline__ void bitonic64(float (&kv)[R], int (&kc)[R], int lane) {
#pragma unroll
  for (int k = 2; k <= 64; k <<= 1) {
#pragma unroll
    for (int j = k >> 1; j > 0; j >>= 1) {
      bool keepmin = ((lane < (lane ^ j)) == ((lane & k) == 0));
#pragma unroll
      for (int r = 0; r < R; ++r) {
        float ov = __shfl_xor(kv[r], j);
        int   oc = __shfl_xor(kc[r], j);
        bool less = (ov < kv[r]) || (ov == kv[r] && oc < kc[r]);
        bool take = keepmin ? less : !less;
        if (take) { kv[r] = ov; kc[r] = oc; }
      }
    }
  }
}

// read-side LDS addressing for staged columns (write is linear via global_load_lds
// with the same involution pre-applied to the global source address)
__device__ __forceinline__ int col_byte(int node, int granule) {
  return node*128 + ((granule ^ (node & 7)) << 4);
}

// ---------------- knn: MFMA Gram (split bf16, precomputed) + exact top-24 ----------------
// 8 staging chunks of 32 KB (256 nodes x one 32-k slice); acc->selection transpose
// done in two 16x512 halves so sRegion stays 32 KB -> 3 blocks/CU.
__global__ void __launch_bounds__(256, 3) k_knn(
    const unsigned char* __restrict__ XB, const float* __restrict__ SQ,
    int* __restrict__ IDX) {
  __shared__ __align__(16) unsigned char sRegion[32768]; // staging -> dist halves -> sCmp
  __shared__ __align__(16) unsigned char sRowB[16*272];  // [row][ks0 hi|lo, ks1 hi|lo] + pad
  __shared__ float sCsq[1024];

  int g = blockIdx.x >> 6;
  int rowBase = (blockIdx.x & 63) * 16;
  int gbase = g * NPG;
  int t = threadIdx.x;
  const int lane = t & 63, wave = t >> 6;
  const int g4 = lane >> 4;      // 0..3
  const int a15 = lane & 15;

  // ---- stage row fragments + column squared norms ----
  {
    int row = t >> 4, part = t & 15;          // part<8 -> ks0, else ks1
    int ks = part >> 3, o = part & 7;
    const unsigned char* src =
        XB + (((size_t)g*2 + ks)*1024 + rowBase + row)*128 + o*16;
    *reinterpret_cast<int4*>(sRowB + row*272 + part*16) =
        *reinterpret_cast<const int4*>(src);
    float4 q = *reinterpret_cast<const float4*>(SQ + gbase + t*4);
    *reinterpret_cast<float4*>(sCsq + t*4) = q;
  }
  __syncthreads();

  // A fragments, both k-slices, hoisted (sRowB stable from here on)
  short8 ahf[2], alf[2];
#pragma unroll
  for (int ks = 0; ks < 2; ++ks) {
    ahf[ks] = *reinterpret_cast<const short8*>(sRowB + a15*272 + ks*128 + (g4 << 4));
    alf[ks] = *reinterpret_cast<const short8*>(sRowB + a15*272 + ks*128 + 64 + (g4 << 4));
  }

  f32x4 acc[16];
#pragma unroll
  for (int i = 0; i < 16; ++i) acc[i] = f32x4{0.f, 0.f, 0.f, 0.f};

  // ---- Gram: acc[ai], ai = h*8 + q*4 + tt2 <-> col h*512 + q*256 + wave*64 + tt2*16 + a15 ----
#pragma unroll
  for (int h = 0; h < 2; ++h) {
#pragma unroll
    for (int q = 0; q < 2; ++q) {
      int colBase = h*512 + q*256;
#pragma unroll
      for (int ks = 0; ks < 2; ++ks) {
        __syncthreads();
        const unsigned char* sl = XB + (((size_t)g*2 + ks)*1024 + colBase)*128;
        // 32 x 1KB wave-chunks; wave owns I = wave*8 + i. LDS linear slot
        // j = I*64+lane -> (node j>>3, gran j&7); source granule pre-swizzled.
#pragma unroll
        for (int i = 0; i < 8; ++i) {
          int I = wave*8 + i;
          int j = I*64 + lane;
          int n = j >> 3, gq = j & 7;
          int srcChunk = (n << 3) + (gq ^ (n & 7));
          gl_lds16(sl + (size_t)srcChunk*16, (void*)(sRegion + I*1024));
        }
        __syncthreads();
#pragma unroll
        for (int tt2 = 0; tt2 < 4; ++tt2) {
          int node = (wave*4 + tt2)*16 + a15;      // local within 256-node chunk
          short8 bh = *reinterpret_cast<const short8*>(sRegion + col_byte(node, g4));
          short8 bl = *reinterpret_cast<const short8*>(sRegion + col_byte(node, 4 + g4));
          int ai = h*8 + q*4 + tt2;
          acc[ai] = __builtin_amdgcn_mfma_f32_16x16x32_bf16(ahf[ks], bh, acc[ai], 0, 0, 0);
          acc[ai] = __builtin_amdgcn_mfma_f32_16x16x32_bf16(ahf[ks], bl, acc[ai], 0, 0, 0);
          acc[ai] = __builtin_amdgcn_mfma_f32_16x16x32_bf16(alf[ks], bh, acc[ai], 0, 0, 0);
          acc[ai] = __builtin_amdgcn_mfma_f32_16x16x32_bf16(alf[ks], bl, acc[ai], 0, 0, 0);
        }
      }
    }
  }

  // ---- transpose acc -> per-wave selection regs, two 16x512 halves ----
  float v[4][16];
  float* dL = (float*)sRegion;   // [16][512]
#pragma unroll
  for (int h = 0; h < 2; ++h) {
    __syncthreads();             // prev reads of sRegion done
#pragma unroll
    for (int aj = 0; aj < 8; ++aj) {
      int ai = h*8 + aj;
      int c512 = (aj >> 2)*256 + wave*64 + (aj & 3)*16 + a15;
      float cs = sCsq[h*512 + c512];
#pragma unroll
      for (int i = 0; i < 4; ++i) {
        int r = g4*4 + i;        // D row = (lane>>4)*4 + reg
        dL[r*512 + c512] = cs - 2.0f*acc[ai][i];
      }
    }
    __syncthreads();
#pragma unroll
    for (int m = 0; m < 8; ++m)
#pragma unroll
      for (int r = 0; r < 4; ++r)
        v[r][h*8 + m] = dL[(wave*4 + r)*512 + lane + 64*m];
  }
  __syncthreads();               // region about to be reused as sCmp

  unsigned long long* sCmp = (unsigned long long*)sRegion; // [4 waves][4 rows][64]

  // phase 2: per-lane argmin per row
  float lm[4]; int lc[4];
#pragma unroll
  for (int r = 0; r < 4; ++r) {
    float bm = v[r][0]; int bc = lane;
#pragma unroll
    for (int m = 1; m < 16; ++m) {
      float vv = v[r][m]; int cc = lane + (m<<6);
      bool b = vv < bm; bm = b ? vv : bm; bc = b ? cc : bc;
    }
    lm[r] = bm; lc[r] = bc;
  }

  // phase 3: sort lane-minima; thr = 24th smallest lane-min
  bitonic64<4>(lm, lc, lane);
  float thr[4];
#pragma unroll
  for (int r = 0; r < 4; ++r) thr[r] = __shfl(lm[r], 23);

  // phase 4: flag, prefix-scan, compact to LDS
  int total[4], excl[4]; unsigned fbits[4];
#pragma unroll
  for (int r = 0; r < 4; ++r) {
    unsigned bits = 0; int cnt = 0;
#pragma unroll
    for (int m = 0; m < 16; ++m) {
      bool f = v[r][m] <= thr[r];
      bits |= ((unsigned)f) << m; cnt += f;
    }
    int pre = cnt;
#pragma unroll
    for (int s = 1; s < 64; s <<= 1) { int o = __shfl_up(pre, s); if (lane >= s) pre += o; }
    total[r] = __shfl(pre, 63);
    excl[r] = pre - cnt; fbits[r] = bits;
  }
#pragma unroll
  for (int r = 0; r < 4; ++r) {
    int slot = excl[r];
#pragma unroll
    for (int m = 0; m < 16; ++m) {
      if ((fbits[r] >> m) & 1) {
        if (slot < 64)
          sCmp[(wave*4 + r)*64 + slot] =
            ((unsigned long long)__float_as_uint(v[r][m]) << 32) | (unsigned)(lane + (m<<6));
        ++slot;
      }
    }
  }
  __syncthreads();

  // phase 5/6: sort compacted candidates, emit top-24
  bool allfast = total[0] <= 64 && total[1] <= 64 && total[2] <= 64 && total[3] <= 64;
  long long ob0 = (long long)(gbase + rowBase + wave*4) * KK;
  if (allfast) {
    float sv[4]; int sc[4];
#pragma unroll
    for (int r = 0; r < 4; ++r) {
      bool in = lane < total[r];
      unsigned long long kp = in ? sCmp[(wave*4 + r)*64 + lane] : 0ull;
      sv[r] = in ? __uint_as_float((unsigned)(kp >> 32)) : FLTMAX;
      sc[r] = in ? (int)(unsigned)kp : 0x7fffffff;
    }
    bitonic64<4>(sv, sc, lane);
#pragma unroll
    for (int r = 0; r < 4; ++r)
      if (lane < KK) IDX[ob0 + (long long)r*KK + lane] = gbase + sc[r];
  } else {
    // cold exact path: fully inlined so v stays in registers
#pragma unroll
    for (int r = 0; r < 4; ++r) {
      unsigned selm = 0;
      for (int it = 0; it < KK; ++it) {
        float bv = FLTMAX; int bj = 0x7fffffff;
#pragma unroll
        for (int m = 0; m < 16; ++m) {
          float vv = ((selm >> m) & 1) ? FLTMAX : v[r][m];
          int col = lane + (m << 6);
          bool b = vv < bv; bv = b ? vv : bv; bj = b ? col : bj;
        }
#pragma unroll
        for (int s = 32; s; s >>= 1) {
          float ov = __shfl_xor(bv, s); int oj = __shfl_xor(bj, s);
          bool b = (ov < bv) || (ov == bv && oj < bj);
          bv = b ? ov : bv; bj = b ? oj : bj;
        }
        if (lane == (bj & 63)) selm |= 1u << (bj >> 6);
        if (lane == 0) IDX[ob0 + (long long)r*KK + it] = gbase + bj;
      }
    }
  }
}

// ---------------- aggregate (in place): F = X + elu(U + max_j V[j]) ----------------
__global__ void __launch_bounds__(256) k_agg(
    const float* __restrict__ U, const float* __restrict__ V,
    const int* __restrict__ IDX, float* __restrict__ F) {
  int tid = blockIdx.x*256 + threadIdx.x;
  int node = tid >> 6;
  int lane = tid & 63;
  const int* idx = IDX + (size_t)node*KK;
  float m = -FLTMAX;
#pragma unroll
  for (int t = 0; t < KK; ++t) {
    int j = idx[t];                          // wave-uniform
    m = fmaxf(m, V[(size_t)j*64 + lane]);
  }
  float s = U[(size_t)node*64 + lane] + m;
  F[(size_t)node*64 + lane] = F[(size_t)node*64 + lane] + elu1(s);
}

// ---------------- output MLP + batch passthrough ----------------
__global__ void __launch_bounds__(256) k_out(
    const float* __restrict__ F, const float* __restrict__ Wo1, const float* __restrict__ bo1,
    const float* __restrict__ Wo2, const float* __restrict__ bo2,
    const float* __restrict__ Wo3, const float* __restrict__ bo3,
    const int* __restrict__ batch, float* __restrict__ out, int out_size) {
  __shared__ float s1[64*64];
  __shared__ float s2[64*32];
  __shared__ float s3[32*8];
  __shared__ float t1[64];
  __shared__ float t2[32];
  __shared__ float t3[8];
  int t = threadIdx.x;
  for (int i = t; i < 64*64; i += 256) s1[i] = Wo1[i];
  for (int i = t; i < 64*32; i += 256) s2[i] = Wo2[i];
  if (t < 32*8) s3[t] = Wo3[t];
  if (t < 64) t1[t] = bo1[t];
  if (t < 32) t2[t] = bo2[t];
  if (t < 8)  t3[t] = bo3[t];
  __syncthreads();
  int node = blockIdx.x*256 + t;
  float f[64];
#pragma unroll
  for (int k = 0; k < 64; ++k) f[k] = F[(size_t)node*64 + k];
  float o1[64];
#pragma unroll 2
  for (int d = 0; d < 64; ++d) {
    float a = t1[d];
#pragma unroll
    for (int k = 0; k < 64; ++k) a += f[k]*s1[k*64+d];
    o1[d] = elu1(a);
  }
  float o2[32];
#pragma unroll 2
  for (int d = 0; d < 32; ++d) {
    float a = t2[d];
#pragma unroll
    for (int k = 0; k < 64; ++k) a += o1[k]*s2[k*32+d];
    o2[d] = elu1(a);
  }
#pragma unroll
  for (int d = 0; d < 8; ++d) {
    float a = t3[d];
#pragma unroll
    for (int k = 0; k < 32; ++k) a += o2[k]*s3[k*8+d];
    out[(size_t)node*8 + d] = a;
  }
  if (out_size >= NN*9) out[(size_t)NN*8 + node] = (float)batch[node];
}

extern "C" void kernel_launch(void* const* d_in, const int* in_sizes, int n_in,
                              void* d_out, int out_size, void* d_ws, size_t ws_size,
                              hipStream_t stream) {
  const float* x     = (const float*)d_in[0];
  const int*   batch = (const int*)d_in[1];
  const float* W1 = (const float*)d_in[2];
  const float* b1 = (const float*)d_in[3];
  const float* W2 = (const float*)d_in[4];
  const float* b2 = (const float*)d_in[5];
  const float* Wc[3] = {(const float*)d_in[6], (const float*)d_in[8], (const float*)d_in[10]};
  const float* bc[3] = {(const float*)d_in[7], (const float*)d_in[9], (const float*)d_in[11]};
  const float* Wo1 = (const float*)d_in[12];
  const float* bo1 = (const float*)d_in[13];
  const float* Wo2 = (const float*)d_in[14];
  const float* bo2 = (const float*)d_in[15];
  const float* Wo3 = (const float*)d_in[16];
  const float* bo3 = (const float*)d_in[17];

  float* ws = (float*)d_ws;
  float* F0 = ws;                               // 8 MB (updated in place per layer)
  float* U  = ws + (size_t)NN*64;               // 8 MB
  float* V  = ws + (size_t)2*NN*64;             // 8 MB
  float* SQ = ws + (size_t)3*NN*64;             // 128 KB
  int*   IDX = (int*)(ws + (size_t)3*NN*64 + NN);           // 3 MB
  unsigned char* XB = (unsigned char*)(IDX + (size_t)NN*KK); // 8 MB split-bf16

  k_mlp_in<<<NN/128, 256, 0, stream>>>(x, W1, b1, W2, b2, F0);
  for (int l = 0; l < 3; ++l) {
    k_uv <<<NN/128, 256, 0, stream>>>(F0, Wc[l], bc[l], U, V, SQ, XB);
    k_knn<<<BG*(NPG/16), 256, 0, stream>>>(XB, SQ, IDX);
    k_agg<<<(NN*64)/256, 256, 0, stream>>>(U, V, IDX, F0);
  }
  k_out<<<NN/256, 256, 0, stream>>>(F0, Wo1, bo1, Wo2, bo2, Wo3, bo3,
                                    batch, (float*)d_out, out_size);
}

// Round 7
// 391.082 us; speedup vs baseline: 1.7143x; 1.1630x over previous
//
#include <hip/hip_runtime.h>
#include <hip/hip_bf16.h>
#include <math.h>

#define NN   32768
#define BG   32
#define NPG  1024
#define HD   64
#define KK   24          // neighbors

#define FLTMAX 3.402823466e38f

typedef __attribute__((ext_vector_type(8))) short short8;
typedef __attribute__((ext_vector_type(4))) float f32x4;

__device__ __forceinline__ float elu1(float x) { return x > 0.f ? x : expm1f(x); }

__device__ __forceinline__ unsigned short f2bf(float x) {  // RNE to bf16
  unsigned u = __float_as_uint(x);
  unsigned r = (u + 0x7FFFu + ((u >> 16) & 1u)) >> 16;
  return (unsigned short)r;
}
__device__ __forceinline__ float bf2f(unsigned short h) {
  return __uint_as_float(((unsigned)h) << 16);
}
// monotone float -> uint order transform (finite values)
__device__ __forceinline__ unsigned ordf(float f) {
  unsigned b = __float_as_uint(f);
  return (b & 0x80000000u) ? ~b : (b | 0x80000000u);
}

// async global->LDS, 16B per lane; lds base must be wave-uniform (HW adds lane*16)
__device__ __forceinline__ void gl_lds16(const void* g, void* lds) {
  __builtin_amdgcn_global_load_lds(
      (const __attribute__((address_space(1))) unsigned int*)g,
      (__attribute__((address_space(3))) unsigned int*)lds, 16, 0, 0);
}

// ---------------- input MLP: h = elu(elu(x@W1+b1)@W2+b2) ----------------
__global__ void __launch_bounds__(256) k_mlp_in(
    const float* __restrict__ x, const float* __restrict__ W1, const float* __restrict__ b1,
    const float* __restrict__ W2, const float* __restrict__ b2, float* __restrict__ F) {
  __shared__ float sW1[8*64];
  __shared__ float sW2[64*64];
  __shared__ float sb1[64];
  __shared__ float sb2[64];
  int t = threadIdx.x;
  for (int i = t; i < 8*64; i += 256) sW1[i] = W1[i];
  for (int i = t; i < 64*64; i += 256) sW2[i] = W2[i];
  if (t < 64) { sb1[t] = b1[t]; sb2[t] = b2[t]; }
  __syncthreads();
  int node = blockIdx.x*128 + (t & 127);
  int half = t >> 7;
  float xr[8];
#pragma unroll
  for (int i = 0; i < 8; ++i) xr[i] = x[node*8 + i];
  float h1[64];
#pragma unroll 8
  for (int k = 0; k < 64; ++k) {
    float a = sb1[k];
#pragma unroll
    for (int i = 0; i < 8; ++i) a += xr[i]*sW1[i*64+k];
    h1[k] = elu1(a);
  }
#pragma unroll 2
  for (int dd = 0; dd < 32; ++dd) {
    int d = half*32 + dd;
    float a = sb2[d];
#pragma unroll
    for (int k = 0; k < 64; ++k) a += h1[k]*sW2[k*64+d];
    F[node*64 + d] = elu1(a);
  }
}

// split-bf16 conv-buffer addressing: per node 16 granules of 16B,
// g = ks*8 + part*4 + oct (part 0=hi,1=lo); XOR swizzle on low 3 bits.
__device__ __forceinline__ int conv_off(int node, int g) {
  return node*256 + ((((g & 7) ^ (node & 7)) | (g & 8)) << 4);
}

// ---- per-layer (MFMA): U = X@(A-B)+bc, V = X@B, SQ, XB = split-bf16(X) ----
__global__ void __launch_bounds__(256) k_uv(
    const float* __restrict__ X, const float* __restrict__ Wc, const float* __restrict__ bc,
    float* __restrict__ U, float* __restrict__ V, float* __restrict__ SQ,
    unsigned char* __restrict__ XB) {
  __shared__ __align__(16) unsigned char sConv[128*256];   // 32 KB node rows (swizzled)
  __shared__ __align__(16) unsigned char sWf[128*256];     // 32 KB B-fragments
  __shared__ float sbc[64];
  int t = threadIdx.x;
  const int lane = t & 63, wave = t >> 6;
  const int g4 = lane >> 4, a15 = lane & 15;
  int base = blockIdx.x * 128;
  int graph = base >> 10;
  int nig0 = base & 1023;

  if (t < 64) sbc[t] = bc[t];

  // ---- phase A: convert 128 rows to split-bf16 (LDS + global XB), SQ ----
  {
    int ln = t >> 1, ks = t & 1;
    const float* src = X + (size_t)(base + ln)*64 + ks*32;
    unsigned hu[16], lu[16];
    float sq = 0.f;
#pragma unroll
    for (int q = 0; q < 8; ++q) {
      float4 f = *reinterpret_cast<const float4*>(src + q*4);
      sq += f.x*f.x + f.y*f.y + f.z*f.z + f.w*f.w;
      unsigned short h0 = f2bf(f.x), h1 = f2bf(f.y), h2 = f2bf(f.z), h3 = f2bf(f.w);
      unsigned short l0 = f2bf(f.x - bf2f(h0)), l1 = f2bf(f.y - bf2f(h1));
      unsigned short l2 = f2bf(f.z - bf2f(h2)), l3 = f2bf(f.w - bf2f(h3));
      hu[q*2]   = (unsigned)h0 | ((unsigned)h1 << 16);
      hu[q*2+1] = (unsigned)h2 | ((unsigned)h3 << 16);
      lu[q*2]   = (unsigned)l0 | ((unsigned)l1 << 16);
      lu[q*2+1] = (unsigned)l2 | ((unsigned)l3 << 16);
    }
    sq += __shfl_xor(sq, 1);
    if (ks == 0) SQ[base + ln] = sq;
    unsigned char* gdst = XB + (((size_t)graph*2 + ks)*1024 + nig0 + ln)*128;
#pragma unroll
    for (int o = 0; o < 4; ++o) {
      int4 hp = make_int4(hu[o*4], hu[o*4+1], hu[o*4+2], hu[o*4+3]);
      int4 lp = make_int4(lu[o*4], lu[o*4+1], lu[o*4+2], lu[o*4+3]);
      *reinterpret_cast<int4*>(sConv + conv_off(ln, ks*8 + o))     = hp;
      *reinterpret_cast<int4*>(sConv + conv_off(ln, ks*8 + 4 + o)) = lp;
      *reinterpret_cast<int4*>(gdst + o*16)      = hp;
      *reinterpret_cast<int4*>(gdst + 64 + o*16) = lp;
    }
  }

  // ---- phase B: build W fragments ----
  {
    int f = t >> 1, colHalf = t & 1;
    int part = f & 1, nt = (f >> 1) & 7, oct = (f >> 4) & 3, ks = f >> 6;
#pragma unroll
    for (int cc = 0; cc < 8; ++cc) {
      int c8 = colHalf*8 + cc;
      int dp = nt*16 + c8;
      const float* wsrc = (dp < 64) ? (Wc + dp) : (Wc + 64*64 + (dp - 64));
      unsigned short sh[8];
#pragma unroll
      for (int j = 0; j < 8; ++j) {
        float w = wsrc[(ks*32 + oct*8 + j)*64];
        unsigned short hi = f2bf(w);
        sh[j] = part ? f2bf(w - bf2f(hi)) : hi;
      }
      *reinterpret_cast<int4*>(sWf + f*256 + c8*16) = make_int4(
          (unsigned)sh[0] | ((unsigned)sh[1] << 16), (unsigned)sh[2] | ((unsigned)sh[3] << 16),
          (unsigned)sh[4] | ((unsigned)sh[5] << 16), (unsigned)sh[6] | ((unsigned)sh[7] << 16));
    }
  }
  __syncthreads();

  // ---- phase C: MFMA ----
  f32x4 acc[2][8];
#pragma unroll
  for (int m = 0; m < 2; ++m)
#pragma unroll
    for (int n = 0; n < 8; ++n) acc[m][n] = f32x4{0.f, 0.f, 0.f, 0.f};
#pragma unroll
  for (int ks = 0; ks < 2; ++ks) {
#pragma unroll
    for (int m = 0; m < 2; ++m) {
      int node = (wave*2 + m)*16 + a15;
      short8 ah = *reinterpret_cast<const short8*>(sConv + conv_off(node, ks*8 + g4));
      short8 al = *reinterpret_cast<const short8*>(sConv + conv_off(node, ks*8 + 4 + g4));
#pragma unroll
      for (int nt = 0; nt < 8; ++nt) {
        int fb = ((ks*4 + g4)*8 + nt)*2;
        short8 bh = *reinterpret_cast<const short8*>(sWf + fb*256 + a15*16);
        short8 bl = *reinterpret_cast<const short8*>(sWf + (fb+1)*256 + a15*16);
        acc[m][nt] = __builtin_amdgcn_mfma_f32_16x16x32_bf16(ah, bh, acc[m][nt], 0, 0, 0);
        acc[m][nt] = __builtin_amdgcn_mfma_f32_16x16x32_bf16(ah, bl, acc[m][nt], 0, 0, 0);
        acc[m][nt] = __builtin_amdgcn_mfma_f32_16x16x32_bf16(al, bh, acc[m][nt], 0, 0, 0);
        acc[m][nt] = __builtin_amdgcn_mfma_f32_16x16x32_bf16(al, bl, acc[m][nt], 0, 0, 0);
      }
    }
  }

  // ---- phase D: epilogue ----
#pragma unroll
  for (int m = 0; m < 2; ++m) {
#pragma unroll
    for (int nt = 0; nt < 4; ++nt) {
      float bcv = sbc[nt*16 + a15];
#pragma unroll
      for (int i = 0; i < 4; ++i) {
        size_t row = base + (wave*2 + m)*16 + g4*4 + i;
        float p = acc[m][nt][i], q = acc[m][nt+4][i];
        U[row*64 + nt*16 + a15] = p - q + bcv;
        V[row*64 + nt*16 + a15] = q;
      }
    }
  }
}

// read-side LDS addressing for staged columns (write is linear via global_load_lds
// with the same involution pre-applied to the global source address)
__device__ __forceinline__ int col_byte(int node, int granule) {
  return node*128 + ((granule ^ (node & 7)) << 4);
}

// ---------------- knn: MFMA Gram + exact top-24 via ballot bisection ----------------
// 512 threads / 8 waves / 32 rows per block. Wave w: row-group rg=w>>2 (MFMA),
// col-slice wc=w&3; selection rows w*4..w*4+3.
__global__ void __launch_bounds__(512, 6) k_knn(
    const unsigned char* __restrict__ XB, const float* __restrict__ SQ,
    int* __restrict__ IDX) {
  __shared__ __align__(16) unsigned char sRegion[32768]; // staging -> dist -> sCmp
  __shared__ __align__(16) unsigned char sRowB[32*272];  // [row][ks0 hi|lo, ks1 hi|lo] + pad
  __shared__ float sCsq[1024];

  int g = blockIdx.x >> 5;               // 32 row-blocks per graph
  int rowBase = (blockIdx.x & 31) * 32;
  int gbase = g * NPG;
  int t = threadIdx.x;
  const int lane = t & 63, w = t >> 6;
  const int g4 = lane >> 4, a15 = lane & 15;
  const int rg = w >> 2, wc = w & 3;

  // ---- stage 32 row fragments + column squared norms ----
  {
    int row = t >> 4, part = t & 15;     // part<8 -> ks0, else ks1
    int ks = part >> 3, o = part & 7;
    const unsigned char* src =
        XB + (((size_t)g*2 + ks)*1024 + rowBase + row)*128 + o*16;
    *reinterpret_cast<int4*>(sRowB + row*272 + part*16) =
        *reinterpret_cast<const int4*>(src);
    if (t < 256) {
      float4 q = *reinterpret_cast<const float4*>(SQ + gbase + t*4);
      *reinterpret_cast<float4*>(sCsq + t*4) = q;
    }
  }

  f32x4 acc[16];
#pragma unroll
  for (int i = 0; i < 16; ++i) acc[i] = f32x4{0.f, 0.f, 0.f, 0.f};

  // ---- Gram: acc[ai], ai = h*8 + q*4 + tt2 <-> chunk col wc*64 + tt2*16 + a15 ----
#pragma unroll
  for (int h = 0; h < 2; ++h) {
#pragma unroll
    for (int q = 0; q < 2; ++q) {
      int colBase = h*512 + q*256;
#pragma unroll
      for (int ks = 0; ks < 2; ++ks) {
        __syncthreads();
        const unsigned char* sl = XB + (((size_t)g*2 + ks)*1024 + colBase)*128;
#pragma unroll
        for (int i = 0; i < 4; ++i) {
          int I = w*4 + i;
          int j = I*64 + lane;
          int n = j >> 3, gq = j & 7;
          int srcChunk = (n << 3) + (gq ^ (n & 7));
          gl_lds16(sl + (size_t)srcChunk*16, (void*)(sRegion + I*1024));
        }
        __syncthreads();
        short8 ah = *reinterpret_cast<const short8*>(
            sRowB + (rg*16 + a15)*272 + ks*128 + (g4 << 4));
        short8 al = *reinterpret_cast<const short8*>(
            sRowB + (rg*16 + a15)*272 + ks*128 + 64 + (g4 << 4));
#pragma unroll
        for (int tt2 = 0; tt2 < 4; ++tt2) {
          int node = wc*64 + tt2*16 + a15;     // within 256-node chunk
          short8 bh = *reinterpret_cast<const short8*>(sRegion + col_byte(node, g4));
          short8 bl = *reinterpret_cast<const short8*>(sRegion + col_byte(node, 4 + g4));
          int ai = h*8 + q*4 + tt2;
          acc[ai] = __builtin_amdgcn_mfma_f32_16x16x32_bf16(ah, bh, acc[ai], 0, 0, 0);
          acc[ai] = __builtin_amdgcn_mfma_f32_16x16x32_bf16(ah, bl, acc[ai], 0, 0, 0);
          acc[ai] = __builtin_amdgcn_mfma_f32_16x16x32_bf16(al, bh, acc[ai], 0, 0, 0);
          acc[ai] = __builtin_amdgcn_mfma_f32_16x16x32_bf16(al, bl, acc[ai], 0, 0, 0);
        }
      }
    }
  }

  // ---- transpose acc -> per-wave selection regs, 4 quarters of [32][256] ----
  // col = m*64 + lane, m = hq*4 + m4. XOR swizzle by row bits[3:2] kills 4-way conflicts.
  float v[4][16];
  float* dL = (float*)sRegion;
#pragma unroll
  for (int hq = 0; hq < 4; ++hq) {
    __syncthreads();               // all reads of sRegion done
#pragma unroll
    for (int tt2 = 0; tt2 < 4; ++tt2) {
      int ai = (hq >> 1)*8 + (hq & 1)*4 + tt2;
      int c256 = wc*64 + tt2*16 + a15;
      float cs = sCsq[hq*256 + c256];
#pragma unroll
      for (int i = 0; i < 4; ++i) {
        int r32 = rg*16 + g4*4 + i;
        dL[r32*256 + (c256 ^ ((r32 & 12) << 2))] = cs - 2.0f*acc[ai][i];
      }
    }
    __syncthreads();
#pragma unroll
    for (int m4 = 0; m4 < 4; ++m4)
#pragma unroll
      for (int r = 0; r < 4; ++r) {
        int rr = w*4 + r;
        v[r][hq*4 + m4] = dL[rr*256 + ((m4*64 + lane) ^ ((rr & 12) << 2))];
      }
  }
  __syncthreads();                 // region about to be reused as sCmp

  unsigned long long* sCmp = (unsigned long long*)sRegion; // [8 waves][4 rows][64]
  const unsigned long long mlt = (1ull << lane) - 1ull;

  // phase 2: per-lane min per row (value only), in ord space
  unsigned uu[4];
#pragma unroll
  for (int r = 0; r < 4; ++r) {
    float bm = v[r][0];
#pragma unroll
    for (int m = 1; m < 16; ++m) bm = fminf(bm, v[r][m]);
    uu[r] = ordf(bm);
  }

  // phase 3: thr = 24th smallest lane-min via 32-step radix bisection (no DS ops)
  unsigned pp[4] = {0u, 0u, 0u, 0u};
#pragma unroll
  for (int b = 31; b >= 0; --b) {
#pragma unroll
    for (int r = 0; r < 4; ++r) {
      unsigned q = pp[r] | (1u << b);
      if ((int)__popcll(__ballot(uu[r] < q)) < KK) pp[r] = q;
    }
  }

  // phase 4: flag (ord <= thr), ballot-compact to sCmp (order-free slots)
  int total[4];
#pragma unroll
  for (int r = 0; r < 4; ++r) {
    int base = 0;
#pragma unroll
    for (int m = 0; m < 16; ++m) {
      unsigned ov = ordf(v[r][m]);
      bool f = ov <= pp[r];
      unsigned long long bal = __ballot(f);
      int slot = base + (int)__popcll(bal & mlt);
      if (f && slot < 64)
        sCmp[(w*4 + r)*64 + slot] =
            ((unsigned long long)ov << 32) | (unsigned)(lane + (m << 6));
      base += (int)__popcll(bal);
    }
    total[r] = base;
  }

  // phase 5: exact top-24 by (dist, col) lex via bisection on compacted candidates
  unsigned cu2[4]; int col2[4];
#pragma unroll
  for (int r = 0; r < 4; ++r) {
    unsigned long long kp = (lane < total[r]) ? sCmp[(w*4 + r)*64 + lane] : ~0ull;
    cu2[r] = (unsigned)(kp >> 32);
    col2[r] = (int)(unsigned)(kp & 0xFFFFFFFFull);
  }
  unsigned p2[4] = {0u, 0u, 0u, 0u};
#pragma unroll
  for (int b = 31; b >= 0; --b) {
#pragma unroll
    for (int r = 0; r < 4; ++r) {
      unsigned q = p2[r] | (1u << b);
      if ((int)__popcll(__ballot(cu2[r] < q)) < KK) p2[r] = q;
    }
  }
  int need[4]; bool tie[4];
#pragma unroll
  for (int r = 0; r < 4; ++r) {
    need[r] = KK - (int)__popcll(__ballot(cu2[r] < p2[r]));
    tie[r] = (cu2[r] == p2[r]);
  }
  unsigned p3[4] = {0u, 0u, 0u, 0u};
#pragma unroll
  for (int b = 9; b >= 0; --b) {
#pragma unroll
    for (int r = 0; r < 4; ++r) {
      unsigned q = p3[r] | (1u << b);
      if ((int)__popcll(__ballot(tie[r] && ((unsigned)col2[r] < q))) < need[r]) p3[r] = q;
    }
  }

  bool allfast = total[0] <= 64 && total[1] <= 64 && total[2] <= 64 && total[3] <= 64;
  long long ob0 = (long long)(gbase + rowBase + w*4) * KK;
  if (allfast) {
#pragma unroll
    for (int r = 0; r < 4; ++r) {
      bool in24 = (cu2[r] < p2[r]) || (tie[r] && ((unsigned)col2[r] <= p3[r]));
      unsigned long long ball = __ballot(in24);
      int pos = (int)__popcll(ball & mlt);
      if (in24) IDX[ob0 + (long long)r*KK + pos] = gbase + col2[r];
    }
  } else {
    // cold exact path: fully inlined so v stays in registers
#pragma unroll
    for (int r = 0; r < 4; ++r) {
      unsigned selm = 0;
      for (int it = 0; it < KK; ++it) {
        float bv = FLTMAX; int bj = 0x7fffffff;
#pragma unroll
        for (int m = 0; m < 16; ++m) {
          float vv = ((selm >> m) & 1) ? FLTMAX : v[r][m];
          int col = lane + (m << 6);
          bool b = vv < bv; bv = b ? vv : bv; bj = b ? col : bj;
        }
#pragma unroll
        for (int s = 32; s; s >>= 1) {
          float ov = __shfl_xor(bv, s); int oj = __shfl_xor(bj, s);
          bool b = (ov < bv) || (ov == bv && oj < bj);
          bv = b ? ov : bv; bj = b ? oj : bj;
        }
        if (lane == (bj & 63)) selm |= 1u << (bj >> 6);
        if (lane == 0) IDX[ob0 + (long long)r*KK + it] = gbase + bj;
      }
    }
  }
}

// ---------------- aggregate (in place): F = X + elu(U + max_j V[j]) ----------------
__global__ void __launch_bounds__(256) k_agg(
    const float* __restrict__ U, const float* __restrict__ V,
    const int* __restrict__ IDX, float* __restrict__ F) {
  int tid = blockIdx.x*256 + threadIdx.x;
  int node = tid >> 6;
  int lane = tid & 63;
  const int* idx = IDX + (size_t)node*KK;
  float m = -FLTMAX;
#pragma unroll
  for (int t = 0; t < KK; ++t) {
    int j = idx[t];                          // wave-uniform
    m = fmaxf(m, V[(size_t)j*64 + lane]);
  }
  float s = U[(size_t)node*64 + lane] + m;
  F[(size_t)node*64 + lane] = F[(size_t)node*64 + lane] + elu1(s);
}

// ---------------- output MLP + batch passthrough ----------------
__global__ void __launch_bounds__(256) k_out(
    const float* __restrict__ F, const float* __restrict__ Wo1, const float* __restrict__ bo1,
    const float* __restrict__ Wo2, const float* __restrict__ bo2,
    const float* __restrict__ Wo3, const float* __restrict__ bo3,
    const int* __restrict__ batch, float* __restrict__ out, int out_size) {
  __shared__ float s1[64*64];
  __shared__ float s2[64*32];
  __shared__ float s3[32*8];
  __shared__ float t1[64];
  __shared__ float t2[32];
  __shared__ float t3[8];
  int t = threadIdx.x;
  for (int i = t; i < 64*64; i += 256) s1[i] = Wo1[i];
  for (int i = t; i < 64*32; i += 256) s2[i] = Wo2[i];
  if (t < 32*8) s3[t] = Wo3[t];
  if (t < 64) t1[t] = bo1[t];
  if (t < 32) t2[t] = bo2[t];
  if (t < 8)  t3[t] = bo3[t];
  __syncthreads();
  int node = blockIdx.x*256 + t;
  float f[64];
#pragma unroll
  for (int k = 0; k < 64; ++k) f[k] = F[(size_t)node*64 + k];
  float o1[64];
#pragma unroll 2
  for (int d = 0; d < 64; ++d) {
    float a = t1[d];
#pragma unroll
    for (int k = 0; k < 64; ++k) a += f[k]*s1[k*64+d];
    o1[d] = elu1(a);
  }
  float o2[32];
#pragma unroll 2
  for (int d = 0; d < 32; ++d) {
    float a = t2[d];
#pragma unroll
    for (int k = 0; k < 64; ++k) a += o1[k]*s2[k*32+d];
    o2[d] = elu1(a);
  }
#pragma unroll
  for (int d = 0; d < 8; ++d) {
    float a = t3[d];
#pragma unroll
    for (int k = 0; k < 32; ++k) a += o2[k]*s3[k*8+d];
    out[(size_t)node*8 + d] = a;
  }
  if (out_size >= NN*9) out[(size_t)NN*8 + node] = (float)batch[node];
}

extern "C" void kernel_launch(void* const* d_in, const int* in_sizes, int n_in,
                              void* d_out, int out_size, void* d_ws, size_t ws_size,
                              hipStream_t stream) {
  const float* x     = (const float*)d_in[0];
  const int*   batch = (const int*)d_in[1];
  const float* W1 = (const float*)d_in[2];
  const float* b1 = (const float*)d_in[3];
  const float* W2 = (const float*)d_in[4];
  const float* b2 = (const float*)d_in[5];
  const float* Wc[3] = {(const float*)d_in[6], (const float*)d_in[8], (const float*)d_in[10]};
  const float* bc[3] = {(const float*)d_in[7], (const float*)d_in[9], (const float*)d_in[11]};
  const float* Wo1 = (const float*)d_in[12];
  const float* bo1 = (const float*)d_in[13];
  const float* Wo2 = (const float*)d_in[14];
  const float* bo2 = (const float*)d_in[15];
  const float* Wo3 = (const float*)d_in[16];
  const float* bo3 = (const float*)d_in[17];

  float* ws = (float*)d_ws;
  float* F0 = ws;                               // 8 MB (updated in place per layer)
  float* U  = ws + (size_t)NN*64;               // 8 MB
  float* V  = ws + (size_t)2*NN*64;             // 8 MB
  float* SQ = ws + (size_t)3*NN*64;             // 128 KB
  int*   IDX = (int*)(ws + (size_t)3*NN*64 + NN);           // 3 MB
  unsigned char* XB = (unsigned char*)(IDX + (size_t)NN*KK); // 8 MB split-bf16

  k_mlp_in<<<NN/128, 256, 0, stream>>>(x, W1, b1, W2, b2, F0);
  for (int l = 0; l < 3; ++l) {
    k_uv <<<NN/128, 256, 0, stream>>>(F0, Wc[l], bc[l], U, V, SQ, XB);
    k_knn<<<BG*(NPG/32), 512, 0, stream>>>(XB, SQ, IDX);
    k_agg<<<(NN*64)/256, 256, 0, stream>>>(U, V, IDX, F0);
  }
  k_out<<<NN/256, 256, 0, stream>>>(F0, Wo1, bo1, Wo2, bo2, Wo3, bo3,
                                    batch, (float*)d_out, out_size);
}

// Round 8
// 371.277 us; speedup vs baseline: 1.8058x; 1.0533x over previous
//
#include <hip/hip_runtime.h>
#include <hip/hip_bf16.h>
#include <math.h>

#define NN   32768
#define BG   32
#define NPG  1024
#define HD   64
#define KK   24          // neighbors

#define FLTMAX 3.402823466e38f

typedef __attribute__((ext_vector_type(8))) short short8;
typedef __attribute__((ext_vector_type(4))) float f32x4;

__device__ __forceinline__ float elu1(float x) { return x > 0.f ? x : expm1f(x); }

__device__ __forceinline__ unsigned short f2bf(float x) {  // RNE to bf16
  unsigned u = __float_as_uint(x);
  unsigned r = (u + 0x7FFFu + ((u >> 16) & 1u)) >> 16;
  return (unsigned short)r;
}
__device__ __forceinline__ float bf2f(unsigned short h) {
  return __uint_as_float(((unsigned)h) << 16);
}
// monotone float -> uint order transform (finite values)
__device__ __forceinline__ unsigned ordf(float f) {
  unsigned b = __float_as_uint(f);
  return (b & 0x80000000u) ? ~b : (b | 0x80000000u);
}

// async global->LDS, 16B per lane; lds base must be wave-uniform (HW adds lane*16)
__device__ __forceinline__ void gl_lds16(const void* g, void* lds) {
  __builtin_amdgcn_global_load_lds(
      (const __attribute__((address_space(1))) unsigned int*)g,
      (__attribute__((address_space(3))) unsigned int*)lds, 16, 0, 0);
}

// ---------------- input MLP: h = elu(elu(x@W1+b1)@W2+b2) ----------------
__global__ void __launch_bounds__(256) k_mlp_in(
    const float* __restrict__ x, const float* __restrict__ W1, const float* __restrict__ b1,
    const float* __restrict__ W2, const float* __restrict__ b2, float* __restrict__ F) {
  __shared__ float sW1[8*64];
  __shared__ float sW2[64*64];
  __shared__ float sb1[64];
  __shared__ float sb2[64];
  int t = threadIdx.x;
  for (int i = t; i < 8*64; i += 256) sW1[i] = W1[i];
  for (int i = t; i < 64*64; i += 256) sW2[i] = W2[i];
  if (t < 64) { sb1[t] = b1[t]; sb2[t] = b2[t]; }
  __syncthreads();
  int node = blockIdx.x*128 + (t & 127);
  int half = t >> 7;
  float xr[8];
#pragma unroll
  for (int i = 0; i < 8; ++i) xr[i] = x[node*8 + i];
  float h1[64];
#pragma unroll 8
  for (int k = 0; k < 64; ++k) {
    float a = sb1[k];
#pragma unroll
    for (int i = 0; i < 8; ++i) a += xr[i]*sW1[i*64+k];
    h1[k] = elu1(a);
  }
#pragma unroll 2
  for (int dd = 0; dd < 32; ++dd) {
    int d = half*32 + dd;
    float a = sb2[d];
#pragma unroll
    for (int k = 0; k < 64; ++k) a += h1[k]*sW2[k*64+d];
    F[node*64 + d] = elu1(a);
  }
}

// split-bf16 conv-buffer addressing: per node 16 granules of 16B,
// g = ks*8 + part*4 + oct (part 0=hi,1=lo); XOR swizzle on low 3 bits.
__device__ __forceinline__ int conv_off(int node, int g) {
  return node*256 + ((((g & 7) ^ (node & 7)) | (g & 8)) << 4);
}

// ---- per-layer (MFMA): U = X@(A-B)+bc, V = X@B, SQ, XB = split-bf16(X) ----
__global__ void __launch_bounds__(256) k_uv(
    const float* __restrict__ X, const float* __restrict__ Wc, const float* __restrict__ bc,
    float* __restrict__ U, float* __restrict__ V, float* __restrict__ SQ,
    unsigned char* __restrict__ XB) {
  __shared__ __align__(16) unsigned char sConv[128*256];   // 32 KB node rows (swizzled)
  __shared__ __align__(16) unsigned char sWf[128*256];     // 32 KB B-fragments
  __shared__ float sbc[64];
  int t = threadIdx.x;
  const int lane = t & 63, wave = t >> 6;
  const int g4 = lane >> 4, a15 = lane & 15;
  int base = blockIdx.x * 128;
  int graph = base >> 10;
  int nig0 = base & 1023;

  if (t < 64) sbc[t] = bc[t];

  // ---- phase A: convert 128 rows to split-bf16 (LDS + global XB), SQ ----
  {
    int ln = t >> 1, ks = t & 1;
    const float* src = X + (size_t)(base + ln)*64 + ks*32;
    unsigned hu[16], lu[16];
    float sq = 0.f;
#pragma unroll
    for (int q = 0; q < 8; ++q) {
      float4 f = *reinterpret_cast<const float4*>(src + q*4);
      sq += f.x*f.x + f.y*f.y + f.z*f.z + f.w*f.w;
      unsigned short h0 = f2bf(f.x), h1 = f2bf(f.y), h2 = f2bf(f.z), h3 = f2bf(f.w);
      unsigned short l0 = f2bf(f.x - bf2f(h0)), l1 = f2bf(f.y - bf2f(h1));
      unsigned short l2 = f2bf(f.z - bf2f(h2)), l3 = f2bf(f.w - bf2f(h3));
      hu[q*2]   = (unsigned)h0 | ((unsigned)h1 << 16);
      hu[q*2+1] = (unsigned)h2 | ((unsigned)h3 << 16);
      lu[q*2]   = (unsigned)l0 | ((unsigned)l1 << 16);
      lu[q*2+1] = (unsigned)l2 | ((unsigned)l3 << 16);
    }
    sq += __shfl_xor(sq, 1);
    if (ks == 0) SQ[base + ln] = sq;
    unsigned char* gdst = XB + (((size_t)graph*2 + ks)*1024 + nig0 + ln)*128;
#pragma unroll
    for (int o = 0; o < 4; ++o) {
      int4 hp = make_int4(hu[o*4], hu[o*4+1], hu[o*4+2], hu[o*4+3]);
      int4 lp = make_int4(lu[o*4], lu[o*4+1], lu[o*4+2], lu[o*4+3]);
      *reinterpret_cast<int4*>(sConv + conv_off(ln, ks*8 + o))     = hp;
      *reinterpret_cast<int4*>(sConv + conv_off(ln, ks*8 + 4 + o)) = lp;
      *reinterpret_cast<int4*>(gdst + o*16)      = hp;
      *reinterpret_cast<int4*>(gdst + 64 + o*16) = lp;
    }
  }

  // ---- phase B: build W fragments ----
  {
    int f = t >> 1, colHalf = t & 1;
    int part = f & 1, nt = (f >> 1) & 7, oct = (f >> 4) & 3, ks = f >> 6;
#pragma unroll
    for (int cc = 0; cc < 8; ++cc) {
      int c8 = colHalf*8 + cc;
      int dp = nt*16 + c8;
      const float* wsrc = (dp < 64) ? (Wc + dp) : (Wc + 64*64 + (dp - 64));
      unsigned short sh[8];
#pragma unroll
      for (int j = 0; j < 8; ++j) {
        float w = wsrc[(ks*32 + oct*8 + j)*64];
        unsigned short hi = f2bf(w);
        sh[j] = part ? f2bf(w - bf2f(hi)) : hi;
      }
      *reinterpret_cast<int4*>(sWf + f*256 + c8*16) = make_int4(
          (unsigned)sh[0] | ((unsigned)sh[1] << 16), (unsigned)sh[2] | ((unsigned)sh[3] << 16),
          (unsigned)sh[4] | ((unsigned)sh[5] << 16), (unsigned)sh[6] | ((unsigned)sh[7] << 16));
    }
  }
  __syncthreads();

  // ---- phase C: MFMA ----
  f32x4 acc[2][8];
#pragma unroll
  for (int m = 0; m < 2; ++m)
#pragma unroll
    for (int n = 0; n < 8; ++n) acc[m][n] = f32x4{0.f, 0.f, 0.f, 0.f};
#pragma unroll
  for (int ks = 0; ks < 2; ++ks) {
#pragma unroll
    for (int m = 0; m < 2; ++m) {
      int node = (wave*2 + m)*16 + a15;
      short8 ah = *reinterpret_cast<const short8*>(sConv + conv_off(node, ks*8 + g4));
      short8 al = *reinterpret_cast<const short8*>(sConv + conv_off(node, ks*8 + 4 + g4));
#pragma unroll
      for (int nt = 0; nt < 8; ++nt) {
        int fb = ((ks*4 + g4)*8 + nt)*2;
        short8 bh = *reinterpret_cast<const short8*>(sWf + fb*256 + a15*16);
        short8 bl = *reinterpret_cast<const short8*>(sWf + (fb+1)*256 + a15*16);
        acc[m][nt] = __builtin_amdgcn_mfma_f32_16x16x32_bf16(ah, bh, acc[m][nt], 0, 0, 0);
        acc[m][nt] = __builtin_amdgcn_mfma_f32_16x16x32_bf16(ah, bl, acc[m][nt], 0, 0, 0);
        acc[m][nt] = __builtin_amdgcn_mfma_f32_16x16x32_bf16(al, bh, acc[m][nt], 0, 0, 0);
        acc[m][nt] = __builtin_amdgcn_mfma_f32_16x16x32_bf16(al, bl, acc[m][nt], 0, 0, 0);
      }
    }
  }

  // ---- phase D: epilogue ----
#pragma unroll
  for (int m = 0; m < 2; ++m) {
#pragma unroll
    for (int nt = 0; nt < 4; ++nt) {
      float bcv = sbc[nt*16 + a15];
#pragma unroll
      for (int i = 0; i < 4; ++i) {
        size_t row = base + (wave*2 + m)*16 + g4*4 + i;
        float p = acc[m][nt][i], q = acc[m][nt+4][i];
        U[row*64 + nt*16 + a15] = p - q + bcv;
        V[row*64 + nt*16 + a15] = q;
      }
    }
  }
}

// read-side LDS addressing for staged columns (write is linear via global_load_lds
// with the same involution pre-applied to the global source address)
__device__ __forceinline__ int col_byte(int node, int granule) {
  return node*128 + ((granule ^ (node & 7)) << 4);
}

// ------- knn + fused aggregate: MFMA Gram, ballot-bisect top-24, gather-max, F update -------
// 512 threads / 8 waves / 32 rows per block. Wave w: row-group rg=w>>2 (MFMA),
// col-slice wc=w&3 (32 cols of each 128-node chunk); selection rows w*4..w*4+3.
// Staging double-buffered: 16 chunks of 128 nodes x one ks-slice (16 KB each),
// stage(c+1) issued BEFORE MFMA(c) with ONE barrier per chunk.
__global__ void __launch_bounds__(512, 6) k_knn(
    const unsigned char* __restrict__ XB, const float* __restrict__ SQ,
    const float* __restrict__ U, const float* __restrict__ V, float* __restrict__ F) {
  __shared__ __align__(16) unsigned char sBuf[32768];    // dbuf 2x16KB -> dist 32KB -> sCmp+nIdx
  __shared__ __align__(16) unsigned char sRowB[32*272];  // [row][ks0 hi|lo, ks1 hi|lo] + pad
  __shared__ float sCsq[1024];

  int g = blockIdx.x >> 5;               // 32 row-blocks per graph
  int rowBase = (blockIdx.x & 31) * 32;
  int gbase = g * NPG;
  int t = threadIdx.x;
  const int lane = t & 63, w = t >> 6;
  const int g4 = lane >> 4, a15 = lane & 15;
  const int rg = w >> 2, wc = w & 3;

  // ---- stage 32 row fragments + column squared norms; issue chunk 0 ----
  {
    int row = t >> 4, part = t & 15;     // part<8 -> ks0, else ks1
    int ks = part >> 3, o = part & 7;
    const unsigned char* src =
        XB + (((size_t)g*2 + ks)*1024 + rowBase + row)*128 + o*16;
    *reinterpret_cast<int4*>(sRowB + row*272 + part*16) =
        *reinterpret_cast<const int4*>(src);
    if (t < 256) {
      float4 q = *reinterpret_cast<const float4*>(SQ + gbase + t*4);
      *reinterpret_cast<float4*>(sCsq + t*4) = q;
    }
  }
  // prologue stage of chunk 0 (ks=0, nodes 0..127) into buffer 0
  {
    const unsigned char* sl = XB + ((size_t)g*2*1024)*128;
#pragma unroll
    for (int i = 0; i < 2; ++i) {
      int I = w*2 + i;                   // 0..15 (16 x 1KB)
      int j = I*64 + lane;
      int n = j >> 3, gq = j & 7;
      int srcChunk = (n << 3) + (gq ^ (n & 7));
      gl_lds16(sl + (size_t)srcChunk*16, (void*)(sBuf + I*1024));
    }
  }
  __syncthreads();                        // rows + csq + chunk 0 ready

  // A fragments, both k-slices, hoisted (sRowB stable from here on)
  short8 ahf[2], alf[2];
#pragma unroll
  for (int ks = 0; ks < 2; ++ks) {
    ahf[ks] = *reinterpret_cast<const short8*>(
        sRowB + (rg*16 + a15)*272 + ks*128 + (g4 << 4));
    alf[ks] = *reinterpret_cast<const short8*>(
        sRowB + (rg*16 + a15)*272 + ks*128 + 64 + (g4 << 4));
  }

  f32x4 acc[16];
#pragma unroll
  for (int i = 0; i < 16; ++i) acc[i] = f32x4{0.f, 0.f, 0.f, 0.f};

  // ---- Gram over 16 chunks: chunk c -> ks=c&1, col block (c>>1)*128 ----
  // acc[ai], ai = (c>>1)*2 + tt  <->  col (c>>1)*128 + wc*32 + tt*16 + a15
#pragma unroll
  for (int c = 0; c < 16; ++c) {
    if (c) __syncthreads();              // chunk c staged; chunk c-1 reads done
    if (c < 15) {
      int cn = c + 1;
      const unsigned char* sl =
          XB + (((size_t)g*2 + (cn & 1))*1024 + (cn >> 1)*128)*128;
#pragma unroll
      for (int i = 0; i < 2; ++i) {
        int I = w*2 + i;
        int j = I*64 + lane;
        int n = j >> 3, gq = j & 7;
        int srcChunk = (n << 3) + (gq ^ (n & 7));
        gl_lds16(sl + (size_t)srcChunk*16, (void*)(sBuf + (cn & 1)*16384 + I*1024));
      }
    }
    const unsigned char* bufc = sBuf + (c & 1)*16384;
    short8 ah = ahf[c & 1], al = alf[c & 1];
#pragma unroll
    for (int tt = 0; tt < 2; ++tt) {
      int node = wc*32 + tt*16 + a15;    // within 128-node chunk
      short8 bh = *reinterpret_cast<const short8*>(bufc + col_byte(node, g4));
      short8 bl = *reinterpret_cast<const short8*>(bufc + col_byte(node, 4 + g4));
      int ai = (c >> 1)*2 + tt;
      acc[ai] = __builtin_amdgcn_mfma_f32_16x16x32_bf16(ah, bh, acc[ai], 0, 0, 0);
      acc[ai] = __builtin_amdgcn_mfma_f32_16x16x32_bf16(ah, bl, acc[ai], 0, 0, 0);
      acc[ai] = __builtin_amdgcn_mfma_f32_16x16x32_bf16(al, bh, acc[ai], 0, 0, 0);
      acc[ai] = __builtin_amdgcn_mfma_f32_16x16x32_bf16(al, bl, acc[ai], 0, 0, 0);
    }
  }

  // ---- transpose acc -> per-wave selection regs, 4 quarters of [32][256] ----
  // quarter hq: ai = hq*4 + k4, col-in-quarter = (k4>>1)*128 + wc*32 + (k4&1)*16 + a15.
  // XOR swizzle by row bits[3:2] kills 4-way conflicts.
  float v[4][16];
  float* dL = (float*)sBuf;              // full 32 KB
#pragma unroll
  for (int hq = 0; hq < 4; ++hq) {
    __syncthreads();                     // all prior reads of sBuf done
#pragma unroll
    for (int k4 = 0; k4 < 4; ++k4) {
      int ai = hq*4 + k4;
      int c256 = (k4 >> 1)*128 + wc*32 + (k4 & 1)*16 + a15;
      float cs = sCsq[hq*256 + c256];
#pragma unroll
      for (int i = 0; i < 4; ++i) {
        int r32 = rg*16 + g4*4 + i;
        dL[r32*256 + (c256 ^ ((r32 & 12) << 2))] = cs - 2.0f*acc[ai][i];
      }
    }
    __syncthreads();
#pragma unroll
    for (int m4 = 0; m4 < 4; ++m4)
#pragma unroll
      for (int r = 0; r < 4; ++r) {
        int rr = w*4 + r;
        v[r][hq*4 + m4] = dL[rr*256 + ((m4*64 + lane) ^ ((rr & 12) << 2))];
      }
  }
  __syncthreads();                       // region about to be reused as sCmp/nIdx

  unsigned long long* sCmp = (unsigned long long*)sBuf;  // [8 waves][4 rows][64] = 16 KB
  int* nIdx = (int*)(sBuf + 16384);                      // [32 rows][24] = 3 KB
  const unsigned long long mlt = (1ull << lane) - 1ull;

  // phase 2: per-lane min per row (value only), in ord space
  unsigned uu[4];
#pragma unroll
  for (int r = 0; r < 4; ++r) {
    float bm = v[r][0];
#pragma unroll
    for (int m = 1; m < 16; ++m) bm = fminf(bm, v[r][m]);
    uu[r] = ordf(bm);
  }

  // phase 3: thr = 24th smallest lane-min via 32-step radix bisection (no DS ops)
  unsigned pp[4] = {0u, 0u, 0u, 0u};
#pragma unroll
  for (int b = 31; b >= 0; --b) {
#pragma unroll
    for (int r = 0; r < 4; ++r) {
      unsigned q = pp[r] | (1u << b);
      if ((int)__popcll(__ballot(uu[r] < q)) < KK) pp[r] = q;
    }
  }

  // phase 4: flag (ord <= thr), ballot-compact to sCmp (order-free slots)
  int total[4];
#pragma unroll
  for (int r = 0; r < 4; ++r) {
    int base = 0;
#pragma unroll
    for (int m = 0; m < 16; ++m) {
      unsigned ov = ordf(v[r][m]);
      bool f = ov <= pp[r];
      unsigned long long bal = __ballot(f);
      int slot = base + (int)__popcll(bal & mlt);
      if (f && slot < 64)
        sCmp[(w*4 + r)*64 + slot] =
            ((unsigned long long)ov << 32) | (unsigned)(lane + (m << 6));
      base += (int)__popcll(bal);
    }
    total[r] = base;
  }

  // phase 5: exact top-24 by (dist, col) lex via bisection on compacted candidates
  unsigned cu2[4]; int col2[4];
#pragma unroll
  for (int r = 0; r < 4; ++r) {
    unsigned long long kp = (lane < total[r]) ? sCmp[(w*4 + r)*64 + lane] : ~0ull;
    cu2[r] = (unsigned)(kp >> 32);
    col2[r] = (int)(unsigned)(kp & 0xFFFFFFFFull);
  }
  unsigned p2[4] = {0u, 0u, 0u, 0u};
#pragma unroll
  for (int b = 31; b >= 0; --b) {
#pragma unroll
    for (int r = 0; r < 4; ++r) {
      unsigned q = p2[r] | (1u << b);
      if ((int)__popcll(__ballot(cu2[r] < q)) < KK) p2[r] = q;
    }
  }
  int need[4]; bool tie[4];
#pragma unroll
  for (int r = 0; r < 4; ++r) {
    need[r] = KK - (int)__popcll(__ballot(cu2[r] < p2[r]));
    tie[r] = (cu2[r] == p2[r]);
  }
  unsigned p3[4] = {0u, 0u, 0u, 0u};
#pragma unroll
  for (int b = 9; b >= 0; --b) {
#pragma unroll
    for (int r = 0; r < 4; ++r) {
      unsigned q = p3[r] | (1u << b);
      if ((int)__popcll(__ballot(tie[r] && ((unsigned)col2[r] < q))) < need[r]) p3[r] = q;
    }
  }

  bool allfast = total[0] <= 64 && total[1] <= 64 && total[2] <= 64 && total[3] <= 64;
  if (allfast) {
#pragma unroll
    for (int r = 0; r < 4; ++r) {
      bool in24 = (cu2[r] < p2[r]) || (tie[r] && ((unsigned)col2[r] <= p3[r]));
      unsigned long long ball = __ballot(in24);
      int pos = (int)__popcll(ball & mlt);
      if (in24) nIdx[(w*4 + r)*KK + pos] = col2[r];      // graph-local col
    }
  } else {
    // cold exact path: fully inlined so v stays in registers
#pragma unroll
    for (int r = 0; r < 4; ++r) {
      unsigned selm = 0;
      for (int it = 0; it < KK; ++it) {
        float bv = FLTMAX; int bj = 0x7fffffff;
#pragma unroll
        for (int m = 0; m < 16; ++m) {
          float vv = ((selm >> m) & 1) ? FLTMAX : v[r][m];
          int col = lane + (m << 6);
          bool b = vv < bv; bv = b ? vv : bv; bj = b ? col : bj;
        }
#pragma unroll
        for (int s = 32; s; s >>= 1) {
          float ov = __shfl_xor(bv, s); int oj = __shfl_xor(bj, s);
          bool b = (ov < bv) || (ov == bv && oj < bj);
          bv = b ? ov : bv; bj = b ? oj : bj;
        }
        if (lane == (bj & 63)) selm |= 1u << (bj >> 6);
        if (lane == 0) nIdx[(w*4 + r)*KK + it] = bj;
      }
    }
  }

  // ---- fused aggregate: F[row] += elu(U[row] + max_j V[j]) (per-wave, own rows) ----
#pragma unroll
  for (int r = 0; r < 4; ++r) {
    int row = rowBase + w*4 + r;         // graph-local
    float mx = -FLTMAX;
#pragma unroll
    for (int tt = 0; tt < KK; ++tt) {
      int j = nIdx[(w*4 + r)*KK + tt];   // wave-uniform broadcast read
      mx = fmaxf(mx, V[((size_t)(gbase + j))*64 + lane]);
    }
    size_t off = (size_t)(gbase + row)*64 + lane;
    F[off] += elu1(U[off] + mx);
  }
}

// ---------------- output MLP + batch passthrough ----------------
__global__ void __launch_bounds__(256) k_out(
    const float* __restrict__ F, const float* __restrict__ Wo1, const float* __restrict__ bo1,
    const float* __restrict__ Wo2, const float* __restrict__ bo2,
    const float* __restrict__ Wo3, const float* __restrict__ bo3,
    const int* __restrict__ batch, float* __restrict__ out, int out_size) {
  __shared__ float s1[64*64];
  __shared__ float s2[64*32];
  __shared__ float s3[32*8];
  __shared__ float t1[64];
  __shared__ float t2[32];
  __shared__ float t3[8];
  int t = threadIdx.x;
  for (int i = t; i < 64*64; i += 256) s1[i] = Wo1[i];
  for (int i = t; i < 64*32; i += 256) s2[i] = Wo2[i];
  if (t < 32*8) s3[t] = Wo3[t];
  if (t < 64) t1[t] = bo1[t];
  if (t < 32) t2[t] = bo2[t];
  if (t < 8)  t3[t] = bo3[t];
  __syncthreads();
  int node = blockIdx.x*256 + t;
  float f[64];
#pragma unroll
  for (int k = 0; k < 64; ++k) f[k] = F[(size_t)node*64 + k];
  float o1[64];
#pragma unroll 2
  for (int d = 0; d < 64; ++d) {
    float a = t1[d];
#pragma unroll
    for (int k = 0; k < 64; ++k) a += f[k]*s1[k*64+d];
    o1[d] = elu1(a);
  }
  float o2[32];
#pragma unroll 2
  for (int d = 0; d < 32; ++d) {
    float a = t2[d];
#pragma unroll
    for (int k = 0; k < 64; ++k) a += o1[k]*s2[k*32+d];
    o2[d] = elu1(a);
  }
#pragma unroll
  for (int d = 0; d < 8; ++d) {
    float a = t3[d];
#pragma unroll
    for (int k = 0; k < 32; ++k) a += o2[k]*s3[k*8+d];
    out[(size_t)node*8 + d] = a;
  }
  if (out_size >= NN*9) out[(size_t)NN*8 + node] = (float)batch[node];
}

extern "C" void kernel_launch(void* const* d_in, const int* in_sizes, int n_in,
                              void* d_out, int out_size, void* d_ws, size_t ws_size,
                              hipStream_t stream) {
  const float* x     = (const float*)d_in[0];
  const int*   batch = (const int*)d_in[1];
  const float* W1 = (const float*)d_in[2];
  const float* b1 = (const float*)d_in[3];
  const float* W2 = (const float*)d_in[4];
  const float* b2 = (const float*)d_in[5];
  const float* Wc[3] = {(const float*)d_in[6], (const float*)d_in[8], (const float*)d_in[10]};
  const float* bc[3] = {(const float*)d_in[7], (const float*)d_in[9], (const float*)d_in[11]};
  const float* Wo1 = (const float*)d_in[12];
  const float* bo1 = (const float*)d_in[13];
  const float* Wo2 = (const float*)d_in[14];
  const float* bo2 = (const float*)d_in[15];
  const float* Wo3 = (const float*)d_in[16];
  const float* bo3 = (const float*)d_in[17];

  float* ws = (float*)d_ws;
  float* F0 = ws;                               // 8 MB (updated in place per layer)
  float* U  = ws + (size_t)NN*64;               // 8 MB
  float* V  = ws + (size_t)2*NN*64;             // 8 MB
  float* SQ = ws + (size_t)3*NN*64;             // 128 KB
  unsigned char* XB = (unsigned char*)(ws + (size_t)3*NN*64 + NN); // 8 MB split-bf16

  k_mlp_in<<<NN/128, 256, 0, stream>>>(x, W1, b1, W2, b2, F0);
  for (int l = 0; l < 3; ++l) {
    k_uv <<<NN/128, 256, 0, stream>>>(F0, Wc[l], bc[l], U, V, SQ, XB);
    k_knn<<<BG*(NPG/32), 512, 0, stream>>>(XB, SQ, U, V, F0);
  }
  k_out<<<NN/256, 256, 0, stream>>>(F0, Wo1, bo1, Wo2, bo2, Wo3, bo3,
                                    batch, (float*)d_out, out_size);
}